// Round 1
// baseline (2240.287 us; speedup 1.0000x reference)
//
#include <hip/hip_runtime.h>
#include <hip/hip_bf16.h>

#define N_NODES 50000

// ---------------- workspace layout (bytes) ----------------
// [0, 200000)                      : deg -> invdeg (50000 f32)
// [262144, 262144+25600000)        : agg1 (50000 x 128 f32)  -- later reused as p (50000 x 64 f32)
// [25862144, 25862144+25600000)    : h    (50000 x 128 f32)
#define DEG_OFF   0
#define AGG_OFF   262144
#define H_OFF     (AGG_OFF + 25600000)
#define WS_NEEDED (H_OFF + 25600000)

// ---- degree: one atomic per edge ----
__global__ __launch_bounds__(256) void deg_kernel(const int* __restrict__ dst,
                                                  float* __restrict__ deg, int E) {
    int e = blockIdx.x * 256 + threadIdx.x;
    if (e < E) atomicAdd(&deg[dst[e]], 1.0f);
}

// ---- invdeg[i] = 1 / max(deg[i], 1) (in place) ----
__global__ __launch_bounds__(256) void invdeg_kernel(float* __restrict__ deg, int n) {
    int i = blockIdx.x * 256 + threadIdx.x;
    if (i < n) deg[i] = 1.0f / fmaxf(deg[i], 1.0f);
}

// ---- layer-1 scatter: agg1[dst] += x[src] * invdeg[dst]  (d=128, 32 lanes/edge x float4) ----
__global__ __launch_bounds__(256) void scatter1_kernel(const int* __restrict__ src,
                                                       const int* __restrict__ dst,
                                                       const float* __restrict__ invdeg,
                                                       const float4* __restrict__ x4,
                                                       float* __restrict__ agg, int E) {
    unsigned idx = blockIdx.x * 256u + threadIdx.x;
    int e = idx >> 5;          // 32 threads per edge
    int part = idx & 31;       // which float4 of the 128-float row
    if (e >= E) return;
    int s = src[e], d = dst[e];
    float inv = invdeg[d];
    float4 v = x4[(size_t)s * 32 + part];
    float* ap = agg + (size_t)d * 128 + part * 4;
    atomicAdd(ap + 0, v.x * inv);
    atomicAdd(ap + 1, v.y * inv);
    atomicAdd(ap + 2, v.z * inv);
    atomicAdd(ap + 3, v.w * inv);
}

// ---- layer-1 dense: h = relu(agg1 @ W_l1 + b1 + x @ W_r1)  (8 nodes/block, 128 threads) ----
__global__ __launch_bounds__(128) void gemm1_kernel(const float* __restrict__ agg,
                                                    const float* __restrict__ x,
                                                    const float* __restrict__ Wl,
                                                    const float* __restrict__ b,
                                                    const float* __restrict__ Wr,
                                                    float* __restrict__ h) {
    __shared__ float sm_m[8][128];
    __shared__ float sm_x[8][128];
    int n0 = blockIdx.x * 8;
    int j = threadIdx.x;
    for (int i = j; i < 8 * 128; i += 128) {
        int n = i >> 7, k = i & 127;
        sm_m[n][k] = agg[(size_t)(n0 + n) * 128 + k];
        sm_x[n][k] = x[(size_t)(n0 + n) * 128 + k];
    }
    __syncthreads();
    float bj = b[j];
    float acc[8];
#pragma unroll
    for (int n = 0; n < 8; ++n) acc[n] = bj;
    for (int k = 0; k < 128; ++k) {
        float wl = Wl[k * 128 + j];
        float wr = Wr[k * 128 + j];
#pragma unroll
        for (int n = 0; n < 8; ++n) acc[n] += sm_m[n][k] * wl + sm_x[n][k] * wr;
    }
#pragma unroll
    for (int n = 0; n < 8; ++n)
        h[(size_t)(n0 + n) * 128 + j] = fmaxf(acc[n], 0.0f);
}

// ---- layer-2 dense: p = h @ W_l2 ; out = b2 + h @ W_r2   (8 nodes/block, 64 threads) ----
__global__ __launch_bounds__(64) void gemm2_kernel(const float* __restrict__ h,
                                                   const float* __restrict__ Wl2,
                                                   const float* __restrict__ b2,
                                                   const float* __restrict__ Wr2,
                                                   float* __restrict__ p,
                                                   float* __restrict__ out) {
    __shared__ float sm_h[8][128];
    int n0 = blockIdx.x * 8;
    int j = threadIdx.x;  // 0..63
    for (int i = j; i < 8 * 128; i += 64) {
        sm_h[i >> 7][i & 127] = h[(size_t)(n0 + (i >> 7)) * 128 + (i & 127)];
    }
    __syncthreads();
    float bj = b2[j];
    float accP[8], accO[8];
#pragma unroll
    for (int n = 0; n < 8; ++n) { accP[n] = 0.0f; accO[n] = bj; }
    for (int k = 0; k < 128; ++k) {
        float wl = Wl2[k * 64 + j];
        float wr = Wr2[k * 64 + j];
#pragma unroll
        for (int n = 0; n < 8; ++n) {
            float hv = sm_h[n][k];
            accP[n] += hv * wl;
            accO[n] += hv * wr;
        }
    }
#pragma unroll
    for (int n = 0; n < 8; ++n) {
        p[(size_t)(n0 + n) * 64 + j] = accP[n];
        out[(size_t)(n0 + n) * 64 + j] = accO[n];
    }
}

// ---- layer-2 scatter: out[dst] += p[src] * invdeg[dst]  (d=64, 16 lanes/edge x float4) ----
__global__ __launch_bounds__(256) void scatter2_kernel(const int* __restrict__ src,
                                                       const int* __restrict__ dst,
                                                       const float* __restrict__ invdeg,
                                                       const float4* __restrict__ p4,
                                                       float* __restrict__ out, int E) {
    unsigned idx = blockIdx.x * 256u + threadIdx.x;
    int e = idx >> 4;          // 16 threads per edge
    int part = idx & 15;
    if (e >= E) return;
    int s = src[e], d = dst[e];
    float inv = invdeg[d];
    float4 v = p4[(size_t)s * 16 + part];
    float* op = out + (size_t)d * 64 + part * 4;
    atomicAdd(op + 0, v.x * inv);
    atomicAdd(op + 1, v.y * inv);
    atomicAdd(op + 2, v.z * inv);
    atomicAdd(op + 3, v.w * inv);
}

extern "C" void kernel_launch(void* const* d_in, const int* in_sizes, int n_in,
                              void* d_out, int out_size, void* d_ws, size_t ws_size,
                              hipStream_t stream) {
    const float* x    = (const float*)d_in[0];
    const int*   ei   = (const int*)d_in[1];
    const float* Wl1  = (const float*)d_in[2];
    const float* b1   = (const float*)d_in[3];
    const float* Wr1  = (const float*)d_in[4];
    const float* Wl2  = (const float*)d_in[5];
    const float* b2   = (const float*)d_in[6];
    const float* Wr2  = (const float*)d_in[7];
    float* out = (float*)d_out;

    const int E = in_sizes[1] / 2;
    const int* src = ei;
    const int* dst = ei + E;

    char* ws = (char*)d_ws;
    float* deg  = (float*)(ws + DEG_OFF);   // becomes invdeg in-place
    float* agg1 = (float*)(ws + AGG_OFF);
    float* h    = (float*)(ws + H_OFF);
    float* p    = (float*)(ws + AGG_OFF);   // reuse agg1 region after gemm1

    // zero deg + agg1 (contiguous prefix of ws)
    hipMemsetAsync(d_ws, 0, AGG_OFF + (size_t)N_NODES * 128 * 4, stream);

    deg_kernel<<<(E + 255) / 256, 256, 0, stream>>>(dst, deg, E);
    invdeg_kernel<<<(N_NODES + 255) / 256, 256, 0, stream>>>(deg, N_NODES);

    // layer 1
    scatter1_kernel<<<(E * 32) / 256, 256, 0, stream>>>(src, dst, deg, (const float4*)x, agg1, E);
    gemm1_kernel<<<N_NODES / 8, 128, 0, stream>>>(agg1, x, Wl1, b1, Wr1, h);

    // layer 2 (project-then-aggregate: mean(h)@Wl2 == mean(h@Wl2))
    gemm2_kernel<<<N_NODES / 8, 64, 0, stream>>>(h, Wl2, b2, Wr2, p, out);
    scatter2_kernel<<<(E * 16) / 256, 256, 0, stream>>>(src, dst, deg, (const float4*)p, out, E);
}

// Round 2
// 485.785 us; speedup vs baseline: 4.6117x; 4.6117x over previous
//
#include <hip/hip_runtime.h>
#include <hip/hip_bf16.h>

#define N_NODES 50000

// ---------------- workspace layout (bytes) ----------------
#define OFF_OFF   0                     // off:  50001 ints (exclusive CSR offsets)
#define CUR_OFF   200192                // cur:  50000 ints (bucket cursors)
#define EBUF_OFF  400384                // ebuf: 800000 ints (src ids, bucketed by dst)
#define CNT_OFF   3600384               // cnt:  50000 ints (degree histogram)
#define INV_OFF   3800576               // invdeg: 50000 f32
#define BUF1_OFF  4000768               // agg1 -> h in place: 50000 x 128 f32 (25.6 MB)
#define BUF2_OFF  29600768              // p: 50000 x 64 f32 (12.8 MB)
// total ~42.4 MB

// ---- degree histogram: one int atomic per edge ----
__global__ __launch_bounds__(256) void hist_kernel(const int* __restrict__ dst,
                                                   int* __restrict__ cnt, int E) {
    int e = blockIdx.x * 256 + threadIdx.x;
    if (e < E) atomicAdd(&cnt[dst[e]], 1);
}

// ---- single-block exclusive scan over 50000 counts -> off, cur ----
#define SCAN_T 1024
__global__ __launch_bounds__(SCAN_T) void scan_kernel(const int* __restrict__ cnt,
                                                      int* __restrict__ off,
                                                      int* __restrict__ cur) {
    __shared__ int sm[SCAN_T];
    int t = threadIdx.x;
    const int CHUNK = (N_NODES + SCAN_T - 1) / SCAN_T;  // 49
    int lo = t * CHUNK;
    int hi = min(lo + CHUNK, N_NODES);
    int s = 0;
    for (int i = lo; i < hi; ++i) s += cnt[i];
    sm[t] = s;
    __syncthreads();
    // Hillis-Steele inclusive scan over 1024 partials
    for (int d = 1; d < SCAN_T; d <<= 1) {
        int v = (t >= d) ? sm[t - d] : 0;
        __syncthreads();
        sm[t] += v;
        __syncthreads();
    }
    int run = sm[t] - s;  // exclusive prefix of this chunk
    for (int i = lo; i < hi; ++i) {
        off[i] = run;
        cur[i] = run;
        run += cnt[i];
    }
    if (t == SCAN_T - 1) off[N_NODES] = sm[SCAN_T - 1];
}

// ---- invdeg[i] = 1 / max(deg, 1) ----
__global__ __launch_bounds__(256) void invdeg_kernel(const int* __restrict__ cnt,
                                                     float* __restrict__ invdeg, int n) {
    int i = blockIdx.x * 256 + threadIdx.x;
    if (i < n) invdeg[i] = 1.0f / fmaxf((float)cnt[i], 1.0f);
}

// ---- bucket fill: CSR edge list grouped by dst (4B int atomics only) ----
__global__ __launch_bounds__(256) void bucket_kernel(const int* __restrict__ src,
                                                     const int* __restrict__ dst,
                                                     int* __restrict__ cur,
                                                     int* __restrict__ ebuf, int E) {
    int e = blockIdx.x * 256 + threadIdx.x;
    if (e < E) {
        int d = dst[e];
        int pos = atomicAdd(&cur[d], 1);
        ebuf[pos] = src[e];
    }
}

// ---- layer-1 gather-aggregate: agg[d] = invdeg[d] * sum_{s in N(d)} x[s]  (d=128) ----
__global__ __launch_bounds__(128) void gather1_kernel(const int* __restrict__ off,
                                                      const int* __restrict__ ebuf,
                                                      const float* __restrict__ invdeg,
                                                      const float* __restrict__ x,
                                                      float* __restrict__ agg) {
    int d = blockIdx.x;
    int j = threadIdx.x;
    int lo = off[d], hi = off[d + 1];
    float acc = 0.0f;
    for (int i = lo; i < hi; ++i) {
        int s = ebuf[i];  // block-uniform -> scalar load
        acc += x[(size_t)s * 128 + j];
    }
    agg[(size_t)d * 128 + j] = acc * invdeg[d];
}

// ---- layer-1 dense: h = relu(agg @ W_l1 + b1 + x @ W_r1), IN PLACE on agg buffer ----
__global__ __launch_bounds__(128) void gemm1_kernel(float* __restrict__ aggh,
                                                    const float* __restrict__ x,
                                                    const float* __restrict__ Wl,
                                                    const float* __restrict__ b,
                                                    const float* __restrict__ Wr) {
    __shared__ float sm_m[8][128];
    __shared__ float sm_x[8][128];
    int n0 = blockIdx.x * 8;
    int j = threadIdx.x;
    for (int i = j; i < 8 * 128; i += 128) {
        int n = i >> 7, k = i & 127;
        sm_m[n][k] = aggh[(size_t)(n0 + n) * 128 + k];
        sm_x[n][k] = x[(size_t)(n0 + n) * 128 + k];
    }
    __syncthreads();
    float bj = b[j];
    float acc[8];
#pragma unroll
    for (int n = 0; n < 8; ++n) acc[n] = bj;
    for (int k = 0; k < 128; ++k) {
        float wl = Wl[k * 128 + j];
        float wr = Wr[k * 128 + j];
#pragma unroll
        for (int n = 0; n < 8; ++n) acc[n] += sm_m[n][k] * wl + sm_x[n][k] * wr;
    }
#pragma unroll
    for (int n = 0; n < 8; ++n)
        aggh[(size_t)(n0 + n) * 128 + j] = fmaxf(acc[n], 0.0f);
}

// ---- layer-2 dense: p = h @ W_l2 ; out = b2 + h @ W_r2 ----
__global__ __launch_bounds__(64) void gemm2_kernel(const float* __restrict__ h,
                                                   const float* __restrict__ Wl2,
                                                   const float* __restrict__ b2,
                                                   const float* __restrict__ Wr2,
                                                   float* __restrict__ p,
                                                   float* __restrict__ out) {
    __shared__ float sm_h[8][128];
    int n0 = blockIdx.x * 8;
    int j = threadIdx.x;  // 0..63
    for (int i = j; i < 8 * 128; i += 64)
        sm_h[i >> 7][i & 127] = h[(size_t)(n0 + (i >> 7)) * 128 + (i & 127)];
    __syncthreads();
    float bj = b2[j];
    float accP[8], accO[8];
#pragma unroll
    for (int n = 0; n < 8; ++n) { accP[n] = 0.0f; accO[n] = bj; }
    for (int k = 0; k < 128; ++k) {
        float wl = Wl2[k * 64 + j];
        float wr = Wr2[k * 64 + j];
#pragma unroll
        for (int n = 0; n < 8; ++n) {
            float hv = sm_h[n][k];
            accP[n] += hv * wl;
            accO[n] += hv * wr;
        }
    }
#pragma unroll
    for (int n = 0; n < 8; ++n) {
        p[(size_t)(n0 + n) * 64 + j] = accP[n];
        out[(size_t)(n0 + n) * 64 + j] = accO[n];
    }
}

// ---- layer-2 gather-aggregate: out[d] += invdeg[d] * sum_{s in N(d)} p[s]  (d=64) ----
__global__ __launch_bounds__(64) void gather2_kernel(const int* __restrict__ off,
                                                     const int* __restrict__ ebuf,
                                                     const float* __restrict__ invdeg,
                                                     const float* __restrict__ p,
                                                     float* __restrict__ out) {
    int d = blockIdx.x;
    int j = threadIdx.x;
    int lo = off[d], hi = off[d + 1];
    float acc = 0.0f;
    for (int i = lo; i < hi; ++i)
        acc += p[(size_t)ebuf[i] * 64 + j];
    out[(size_t)d * 64 + j] += acc * invdeg[d];
}

extern "C" void kernel_launch(void* const* d_in, const int* in_sizes, int n_in,
                              void* d_out, int out_size, void* d_ws, size_t ws_size,
                              hipStream_t stream) {
    const float* x   = (const float*)d_in[0];
    const int*   ei  = (const int*)d_in[1];
    const float* Wl1 = (const float*)d_in[2];
    const float* b1  = (const float*)d_in[3];
    const float* Wr1 = (const float*)d_in[4];
    const float* Wl2 = (const float*)d_in[5];
    const float* b2  = (const float*)d_in[6];
    const float* Wr2 = (const float*)d_in[7];
    float* out = (float*)d_out;

    const int E = in_sizes[1] / 2;
    const int* src = ei;
    const int* dst = ei + E;

    char* ws = (char*)d_ws;
    int*   off    = (int*)(ws + OFF_OFF);
    int*   cur    = (int*)(ws + CUR_OFF);
    int*   ebuf   = (int*)(ws + EBUF_OFF);
    int*   cnt    = (int*)(ws + CNT_OFF);
    float* invdeg = (float*)(ws + INV_OFF);
    float* buf1   = (float*)(ws + BUF1_OFF);  // agg1 -> h (in place)
    float* p      = (float*)(ws + BUF2_OFF);

    // zero only the histogram
    hipMemsetAsync(cnt, 0, N_NODES * sizeof(int), stream);

    // build dst-CSR
    hist_kernel<<<(E + 255) / 256, 256, 0, stream>>>(dst, cnt, E);
    scan_kernel<<<1, SCAN_T, 0, stream>>>(cnt, off, cur);
    invdeg_kernel<<<(N_NODES + 255) / 256, 256, 0, stream>>>(cnt, invdeg, N_NODES);
    bucket_kernel<<<(E + 255) / 256, 256, 0, stream>>>(src, dst, cur, ebuf, E);

    // layer 1
    gather1_kernel<<<N_NODES, 128, 0, stream>>>(off, ebuf, invdeg, x, buf1);
    gemm1_kernel<<<N_NODES / 8, 128, 0, stream>>>(buf1, x, Wl1, b1, Wr1);

    // layer 2 (project-then-aggregate: mean(h)@Wl2 == mean(h@Wl2))
    gemm2_kernel<<<N_NODES / 8, 64, 0, stream>>>(buf1, Wl2, b2, Wr2, p, out);
    gather2_kernel<<<N_NODES, 64, 0, stream>>>(off, ebuf, invdeg, p, out);
}

// Round 3
// 366.758 us; speedup vs baseline: 6.1084x; 1.3245x over previous
//
#include <hip/hip_runtime.h>
#include <hip/hip_bf16.h>

#define N_NODES 50000
#define M_TILES 3125   // 50000/16

typedef __attribute__((ext_vector_type(8))) __bf16 bf16x8;
typedef __attribute__((ext_vector_type(4))) float f32x4;

// ---------------- workspace layout (bytes) ----------------
#define OFF_OFF   0            // off:  50001 int
#define CUR_OFF   200192      // cur:  50000 int
#define EBUF_OFF  400384      // ebuf: 800000 int
#define CNT_OFF   3600384     // cnt:  50000 int
#define INV_OFF   3800576     // invdeg: 50000 f32
#define XBF_OFF   4000768     // x_bf:   50000x128 bf16 (12.8 MB)
#define AGG_OFF   16800768    // agg_bf: 50000x128 bf16
#define HBF_OFF   29600768    // h_bf:   50000x128 bf16
#define PBF_OFF   42400768    // p_bf:   50000x64  bf16 (6.4 MB)
#define WP1_OFF   48800768    // Wp1: 256x128 bf16 (64 KB)
#define WP2_OFF   48866304    // Wp2: 128x128 bf16 (32 KB)

// float -> bf16 bits (RNE), returned in high 16
__device__ __forceinline__ unsigned bfbits(float f) {
    unsigned u = __float_as_uint(f);
    return (u + 0x7fffu + ((u >> 16) & 1u)) & 0xffff0000u;
}
__device__ __forceinline__ unsigned short bf16r(float f) {
    return (unsigned short)(bfbits(f) >> 16);
}

// ---- x (f32) -> x_bf ----
__global__ __launch_bounds__(256) void conv_kernel(const float4* __restrict__ x4,
                                                   uint2* __restrict__ xbf, int n4) {
    int i = blockIdx.x * 256 + threadIdx.x;
    if (i >= n4) return;
    float4 v = x4[i];
    uint2 o;
    o.x = (bfbits(v.x) >> 16) | bfbits(v.y);
    o.y = (bfbits(v.z) >> 16) | bfbits(v.w);
    xbf[i] = o;
}

// ---- pack W into B-fragment layout: Wp[((k/32)*128 + n)*32 + ((k>>3)&3)*8 + (k&7)] ----
__global__ __launch_bounds__(256) void pack1_kernel(const float* __restrict__ Wl,
                                                    const float* __restrict__ Wr,
                                                    unsigned short* __restrict__ Wp) {
    int idx = blockIdx.x * 256 + threadIdx.x;  // 256*128
    if (idx >= 256 * 128) return;
    int k = idx >> 7, n = idx & 127;
    float v = (k < 128) ? Wl[k * 128 + n] : Wr[(k - 128) * 128 + n];
    Wp[((k >> 5) << 12) + (n << 5) + (((k >> 3) & 3) << 3) + (k & 7)] = bf16r(v);
}
__global__ __launch_bounds__(256) void pack2_kernel(const float* __restrict__ Wl,
                                                    const float* __restrict__ Wr,
                                                    unsigned short* __restrict__ Wp) {
    int idx = blockIdx.x * 256 + threadIdx.x;  // 128*128
    if (idx >= 128 * 128) return;
    int k = idx >> 7, n = idx & 127;
    float v = (n < 64) ? Wl[k * 64 + n] : Wr[k * 64 + (n - 64)];
    Wp[((k >> 5) << 12) + (n << 5) + (((k >> 3) & 3) << 3) + (k & 7)] = bf16r(v);
}

// ---- degree histogram ----
__global__ __launch_bounds__(256) void hist_kernel(const int* __restrict__ dst,
                                                   int* __restrict__ cnt, int E) {
    int e = blockIdx.x * 256 + threadIdx.x;
    if (e < E) atomicAdd(&cnt[dst[e]], 1);
}

// ---- single-block scan -> off, cur, invdeg ----
#define SCAN_T 1024
__global__ __launch_bounds__(SCAN_T) void scan_kernel(const int* __restrict__ cnt,
                                                      int* __restrict__ off,
                                                      int* __restrict__ cur,
                                                      float* __restrict__ invdeg) {
    __shared__ int sm[SCAN_T];
    int t = threadIdx.x;
    const int CHUNK = (N_NODES + SCAN_T - 1) / SCAN_T;
    int lo = t * CHUNK;
    int hi = min(lo + CHUNK, N_NODES);
    int s = 0;
    for (int i = lo; i < hi; ++i) s += cnt[i];
    sm[t] = s;
    __syncthreads();
    for (int d = 1; d < SCAN_T; d <<= 1) {
        int v = (t >= d) ? sm[t - d] : 0;
        __syncthreads();
        sm[t] += v;
        __syncthreads();
    }
    int run = sm[t] - s;
    for (int i = lo; i < hi; ++i) {
        int c = cnt[i];
        off[i] = run;
        cur[i] = run;
        invdeg[i] = 1.0f / fmaxf((float)c, 1.0f);
        run += c;
    }
    if (t == SCAN_T - 1) off[N_NODES] = sm[SCAN_T - 1];
}

// ---- bucket fill (dst-CSR) ----
__global__ __launch_bounds__(256) void bucket_kernel(const int* __restrict__ src,
                                                     const int* __restrict__ dst,
                                                     int* __restrict__ cur,
                                                     int* __restrict__ ebuf, int E) {
    int e = blockIdx.x * 256 + threadIdx.x;
    if (e < E) {
        int pos = atomicAdd(&cur[dst[e]], 1);
        ebuf[pos] = src[e];
    }
}

// ---- layer-1 gather: agg_bf[d] = invdeg[d] * sum x_bf[s]  (64 lanes x 2 feats) ----
__global__ __launch_bounds__(64) void gather1_kernel(const int* __restrict__ off,
                                                     const int* __restrict__ ebuf,
                                                     const float* __restrict__ invdeg,
                                                     const unsigned* __restrict__ xbf,
                                                     unsigned* __restrict__ aggbf) {
    int d = blockIdx.x;
    int j = threadIdx.x;  // 0..63 -> features 2j, 2j+1
    int lo = off[d], hi = off[d + 1];
    float a0 = 0.0f, a1 = 0.0f;
    for (int i = lo; i < hi; ++i) {
        int s = ebuf[i];
        unsigned v = xbf[s * 64 + j];
        a0 += __uint_as_float(v << 16);
        a1 += __uint_as_float(v & 0xffff0000u);
    }
    float inv = invdeg[d];
    aggbf[d * 64 + j] = (bfbits(a0 * inv) >> 16) | bfbits(a1 * inv);
}

// ---- MFMA gemm1: h = relu([agg|x] @ Wp1 + b1) ; M=50000 K=256 N=128 ----
__global__ __launch_bounds__(256) void gemm1_kernel(const unsigned short* __restrict__ aggbf,
                                                    const unsigned short* __restrict__ xbf,
                                                    const unsigned short* __restrict__ Wp1,
                                                    const float* __restrict__ b1,
                                                    unsigned short* __restrict__ hbf) {
    int tile = blockIdx.x * 4 + (threadIdx.x >> 6);
    if (tile >= M_TILES) return;
    int lane = threadIdx.x & 63;
    int lo16 = lane & 15;
    int kg = lane >> 4;
    int m0 = tile * 16;

    f32x4 acc[8];
#pragma unroll
    for (int n = 0; n < 8; ++n) acc[n] = (f32x4){0.f, 0.f, 0.f, 0.f};

    int arow = m0 + lo16;
    const unsigned short* rowa = aggbf + (size_t)arow * 128;
    const unsigned short* rowx = xbf + (size_t)arow * 128;

#pragma unroll
    for (int ks = 0; ks < 8; ++ks) {
        const unsigned short* abase =
            (ks < 4 ? rowa + ks * 32 : rowx + (ks - 4) * 32) + kg * 8;
        bf16x8 a = *reinterpret_cast<const bf16x8*>(abase);
        const unsigned short* wbase = Wp1 + ks * 4096 + lo16 * 32 + kg * 8;
#pragma unroll
        for (int n = 0; n < 8; ++n) {
            bf16x8 b = *reinterpret_cast<const bf16x8*>(wbase + n * 512);
            acc[n] = __builtin_amdgcn_mfma_f32_16x16x32_bf16(a, b, acc[n], 0, 0, 0);
        }
    }

    int r0 = (lane >> 4) * 4;
#pragma unroll
    for (int n = 0; n < 8; ++n) {
        int col = n * 16 + lo16;
        float bv = b1[col];
#pragma unroll
        for (int r = 0; r < 4; ++r) {
            int row = m0 + r0 + r;
            float v = acc[n][r] + bv;
            hbf[(size_t)row * 128 + col] = bf16r(fmaxf(v, 0.0f));
        }
    }
}

// ---- MFMA gemm2: [p | out] = h @ Wp2 (+b2 on right half) ; M=50000 K=128 N=128 ----
__global__ __launch_bounds__(256) void gemm2_kernel(const unsigned short* __restrict__ hbf,
                                                    const unsigned short* __restrict__ Wp2,
                                                    const float* __restrict__ b2,
                                                    unsigned short* __restrict__ pbf,
                                                    float* __restrict__ out) {
    int tile = blockIdx.x * 4 + (threadIdx.x >> 6);
    if (tile >= M_TILES) return;
    int lane = threadIdx.x & 63;
    int lo16 = lane & 15;
    int kg = lane >> 4;
    int m0 = tile * 16;

    f32x4 acc[8];
#pragma unroll
    for (int n = 0; n < 8; ++n) acc[n] = (f32x4){0.f, 0.f, 0.f, 0.f};

    const unsigned short* rowh = hbf + (size_t)(m0 + lo16) * 128;

#pragma unroll
    for (int ks = 0; ks < 4; ++ks) {
        bf16x8 a = *reinterpret_cast<const bf16x8*>(rowh + ks * 32 + kg * 8);
        const unsigned short* wbase = Wp2 + ks * 4096 + lo16 * 32 + kg * 8;
#pragma unroll
        for (int n = 0; n < 8; ++n) {
            bf16x8 b = *reinterpret_cast<const bf16x8*>(wbase + n * 512);
            acc[n] = __builtin_amdgcn_mfma_f32_16x16x32_bf16(a, b, acc[n], 0, 0, 0);
        }
    }

    int r0 = (lane >> 4) * 4;
#pragma unroll
    for (int n = 0; n < 8; ++n) {
        int col = n * 16 + lo16;
        if (col < 64) {
#pragma unroll
            for (int r = 0; r < 4; ++r) {
                int row = m0 + r0 + r;
                pbf[(size_t)row * 64 + col] = bf16r(acc[n][r]);
            }
        } else {
            float bv = b2[col - 64];
#pragma unroll
            for (int r = 0; r < 4; ++r) {
                int row = m0 + r0 + r;
                out[(size_t)row * 64 + (col - 64)] = acc[n][r] + bv;
            }
        }
    }
}

// ---- layer-2 gather: out[d] += invdeg[d] * sum p_bf[s] ----
__global__ __launch_bounds__(64) void gather2_kernel(const int* __restrict__ off,
                                                     const int* __restrict__ ebuf,
                                                     const float* __restrict__ invdeg,
                                                     const unsigned short* __restrict__ pbf,
                                                     float* __restrict__ out) {
    int d = blockIdx.x;
    int j = threadIdx.x;  // 0..63
    int lo = off[d], hi = off[d + 1];
    float acc = 0.0f;
    for (int i = lo; i < hi; ++i) {
        unsigned v = (unsigned)pbf[ebuf[i] * 64 + j];
        acc += __uint_as_float(v << 16);
    }
    out[d * 64 + j] += acc * invdeg[d];
}

extern "C" void kernel_launch(void* const* d_in, const int* in_sizes, int n_in,
                              void* d_out, int out_size, void* d_ws, size_t ws_size,
                              hipStream_t stream) {
    const float* x   = (const float*)d_in[0];
    const int*   ei  = (const int*)d_in[1];
    const float* Wl1 = (const float*)d_in[2];
    const float* b1  = (const float*)d_in[3];
    const float* Wr1 = (const float*)d_in[4];
    const float* Wl2 = (const float*)d_in[5];
    const float* b2  = (const float*)d_in[6];
    const float* Wr2 = (const float*)d_in[7];
    float* out = (float*)d_out;

    const int E = in_sizes[1] / 2;
    const int* src = ei;
    const int* dst = ei + E;

    char* ws = (char*)d_ws;
    int*            off    = (int*)(ws + OFF_OFF);
    int*            cur    = (int*)(ws + CUR_OFF);
    int*            ebuf   = (int*)(ws + EBUF_OFF);
    int*            cnt    = (int*)(ws + CNT_OFF);
    float*          invdeg = (float*)(ws + INV_OFF);
    unsigned*       xbf    = (unsigned*)(ws + XBF_OFF);
    unsigned*       aggbf  = (unsigned*)(ws + AGG_OFF);
    unsigned short* hbf    = (unsigned short*)(ws + HBF_OFF);
    unsigned short* pbf    = (unsigned short*)(ws + PBF_OFF);
    unsigned short* Wp1    = (unsigned short*)(ws + WP1_OFF);
    unsigned short* Wp2    = (unsigned short*)(ws + WP2_OFF);

    hipMemsetAsync(cnt, 0, N_NODES * sizeof(int), stream);

    conv_kernel<<<(N_NODES * 32 + 255) / 256, 256, 0, stream>>>((const float4*)x, (uint2*)xbf,
                                                                N_NODES * 32);
    pack1_kernel<<<128, 256, 0, stream>>>(Wl1, Wr1, Wp1);
    pack2_kernel<<<64, 256, 0, stream>>>(Wl2, Wr2, Wp2);

    hist_kernel<<<(E + 255) / 256, 256, 0, stream>>>(dst, cnt, E);
    scan_kernel<<<1, SCAN_T, 0, stream>>>(cnt, off, cur, invdeg);
    bucket_kernel<<<(E + 255) / 256, 256, 0, stream>>>(src, dst, cur, ebuf, E);

    // layer 1
    gather1_kernel<<<N_NODES, 64, 0, stream>>>(off, ebuf, invdeg, xbf, aggbf);
    gemm1_kernel<<<(M_TILES + 3) / 4, 256, 0, stream>>>((const unsigned short*)aggbf,
                                                        (const unsigned short*)xbf, Wp1, b1, hbf);

    // layer 2 (project-then-aggregate)
    gemm2_kernel<<<(M_TILES + 3) / 4, 256, 0, stream>>>(hbf, Wp2, b2, pbf, out);
    gather2_kernel<<<N_NODES, 64, 0, stream>>>(off, ebuf, invdeg, pbf, out);
}

// Round 5
// 241.789 us; speedup vs baseline: 9.2654x; 1.5168x over previous
//
#include <hip/hip_runtime.h>
#include <hip/hip_bf16.h>

#define N_NODES 50000
#define M_TILES 3125   // 50000/16
#define SCAN_BLOCKS ((N_NODES + 255) / 256)   // 196

typedef __attribute__((ext_vector_type(8))) __bf16 bf16x8;
typedef __attribute__((ext_vector_type(4))) float f32x4;

// ---------------- workspace layout (bytes) ----------------
#define OFF_OFF   0            // off:  50001 int
#define CUR_OFF   200192      // cur:  50000 int
#define EBUF_OFF  400384      // ebuf: 800000 int
#define CNT_OFF   3600384     // cnt:  50000 int
#define INV_OFF   3800576     // invdeg: 50000 f32
#define XBF_OFF   4000768     // x_bf:   50000x128 bf16 (12.8 MB)
#define AGG_OFF   16800768    // agg_bf: 50000x128 bf16
#define HBF_OFF   29600768    // h_bf:   50000x128 bf16
#define PBF_OFF   42400768    // p_bf:   50000x64  bf16 (6.4 MB); bsum borrows this early
#define WP1_OFF   48800768    // Wp1: 256x128 bf16 (64 KB)
#define WP2_OFF   48866304    // Wp2: 128x128 bf16 (32 KB)

// float -> bf16 bits (RNE), returned in high 16
__device__ __forceinline__ unsigned bfbits(float f) {
    unsigned u = __float_as_uint(f);
    return (u + 0x7fffu + ((u >> 16) & 1u)) & 0xffff0000u;
}
__device__ __forceinline__ unsigned short bf16r(float f) {
    return (unsigned short)(bfbits(f) >> 16);
}

// ---- x (f32) -> x_bf ----
__global__ __launch_bounds__(256) void conv_kernel(const float4* __restrict__ x4,
                                                   uint2* __restrict__ xbf, int n4) {
    int i = blockIdx.x * 256 + threadIdx.x;
    if (i >= n4) return;
    float4 v = x4[i];
    uint2 o;
    o.x = (bfbits(v.x) >> 16) | bfbits(v.y);
    o.y = (bfbits(v.z) >> 16) | bfbits(v.w);
    xbf[i] = o;
}

// ---- pack W into B-fragment layout: Wp[((k/32)*128 + n)*32 + ((k>>3)&3)*8 + (k&7)] ----
__global__ __launch_bounds__(256) void pack1_kernel(const float* __restrict__ Wl,
                                                    const float* __restrict__ Wr,
                                                    unsigned short* __restrict__ Wp) {
    int idx = blockIdx.x * 256 + threadIdx.x;  // 256*128
    if (idx >= 256 * 128) return;
    int k = idx >> 7, n = idx & 127;
    float v = (k < 128) ? Wl[k * 128 + n] : Wr[(k - 128) * 128 + n];
    Wp[((k >> 5) << 12) + (n << 5) + (((k >> 3) & 3) << 3) + (k & 7)] = bf16r(v);
}
__global__ __launch_bounds__(256) void pack2_kernel(const float* __restrict__ Wl,
                                                    const float* __restrict__ Wr,
                                                    unsigned short* __restrict__ Wp) {
    int idx = blockIdx.x * 256 + threadIdx.x;  // 128*128
    if (idx >= 128 * 128) return;
    int k = idx >> 7, n = idx & 127;
    float v = (n < 64) ? Wl[k * 64 + n] : Wr[k * 64 + (n - 64)];
    Wp[((k >> 5) << 12) + (n << 5) + (((k >> 3) & 3) << 3) + (k & 7)] = bf16r(v);
}

// ---- degree histogram ----
__global__ __launch_bounds__(256) void hist_kernel(const int* __restrict__ dst,
                                                   int* __restrict__ cnt, int E) {
    int e = blockIdx.x * 256 + threadIdx.x;
    if (e < E) atomicAdd(&cnt[dst[e]], 1);
}

// ---- scan phase A: per-block (256 nodes) sums ----
__global__ __launch_bounds__(256) void scanA_kernel(const int* __restrict__ cnt,
                                                    int* __restrict__ bsum) {
    __shared__ int sm[4];
    int i = blockIdx.x * 256 + threadIdx.x;
    int v = (i < N_NODES) ? cnt[i] : 0;
    for (int d = 32; d; d >>= 1) v += __shfl_down(v, d, 64);
    if ((threadIdx.x & 63) == 0) sm[threadIdx.x >> 6] = v;
    __syncthreads();
    if (threadIdx.x == 0) bsum[blockIdx.x] = sm[0] + sm[1] + sm[2] + sm[3];
}

// ---- scan phase B: exclusive scan of 196 block sums (one tiny block) ----
__global__ __launch_bounds__(256) void scanB_kernel(int* __restrict__ bsum, int nb) {
    __shared__ int sm[256];
    int t = threadIdx.x;
    int v = (t < nb) ? bsum[t] : 0;
    sm[t] = v;
    __syncthreads();
    for (int d = 1; d < 256; d <<= 1) {
        int u = (t >= d) ? sm[t - d] : 0;
        __syncthreads();
        sm[t] += u;
        __syncthreads();
    }
    if (t < nb) bsum[t] = sm[t] - v;  // exclusive
}

// ---- scan phase C: per-block exclusive rescan + global offset -> off, cur, invdeg ----
__global__ __launch_bounds__(256) void scanC_kernel(const int* __restrict__ cnt,
                                                    const int* __restrict__ bsum,
                                                    int* __restrict__ off,
                                                    int* __restrict__ cur,
                                                    float* __restrict__ invdeg) {
    __shared__ int sm[256];
    int t = threadIdx.x;
    int i = blockIdx.x * 256 + t;
    int c = (i < N_NODES) ? cnt[i] : 0;
    sm[t] = c;
    __syncthreads();
    for (int d = 1; d < 256; d <<= 1) {
        int u = (t >= d) ? sm[t - d] : 0;
        __syncthreads();
        sm[t] += u;
        __syncthreads();
    }
    int excl = sm[t] - c + bsum[blockIdx.x];
    if (i < N_NODES) {
        off[i] = excl;
        cur[i] = excl;
        invdeg[i] = 1.0f / fmaxf((float)c, 1.0f);
        if (i == N_NODES - 1) off[N_NODES] = excl + c;
    }
}

// ---- bucket fill (dst-CSR) ----
__global__ __launch_bounds__(256) void bucket_kernel(const int* __restrict__ src,
                                                     const int* __restrict__ dst,
                                                     int* __restrict__ cur,
                                                     int* __restrict__ ebuf, int E) {
    int e = blockIdx.x * 256 + threadIdx.x;
    if (e < E) {
        int pos = atomicAdd(&cur[dst[e]], 1);
        ebuf[pos] = src[e];
    }
}

// ---- layer-1 gather: agg_bf[d] = invdeg[d] * sum x_bf[s]  (64 lanes x 2 feats) ----
__global__ __launch_bounds__(64) void gather1_kernel(const int* __restrict__ off,
                                                     const int* __restrict__ ebuf,
                                                     const float* __restrict__ invdeg,
                                                     const unsigned* __restrict__ xbf,
                                                     unsigned* __restrict__ aggbf) {
    int d = blockIdx.x;
    int j = threadIdx.x;  // 0..63 -> features 2j, 2j+1
    int lo = off[d], hi = off[d + 1];
    float a0 = 0.0f, a1 = 0.0f;
    for (int i = lo; i < hi; ++i) {
        int s = ebuf[i];
        unsigned v = xbf[s * 64 + j];
        a0 += __uint_as_float(v << 16);
        a1 += __uint_as_float(v & 0xffff0000u);
    }
    float inv = invdeg[d];
    aggbf[d * 64 + j] = (bfbits(a0 * inv) >> 16) | bfbits(a1 * inv);
}

// ---- MFMA gemm1: h = relu([agg|x] @ Wp1 + b1) ; M=50000 K=256 N=128 ----
__global__ __launch_bounds__(256) void gemm1_kernel(const unsigned short* __restrict__ aggbf,
                                                    const unsigned short* __restrict__ xbf,
                                                    const unsigned short* __restrict__ Wp1,
                                                    const float* __restrict__ b1,
                                                    unsigned short* __restrict__ hbf) {
    int tile = blockIdx.x * 4 + (threadIdx.x >> 6);
    if (tile >= M_TILES) return;
    int lane = threadIdx.x & 63;
    int lo16 = lane & 15;
    int kg = lane >> 4;
    int m0 = tile * 16;

    f32x4 acc[8];
#pragma unroll
    for (int n = 0; n < 8; ++n) acc[n] = (f32x4){0.f, 0.f, 0.f, 0.f};

    int arow = m0 + lo16;
    const unsigned short* rowa = aggbf + (size_t)arow * 128;
    const unsigned short* rowx = xbf + (size_t)arow * 128;

#pragma unroll
    for (int ks = 0; ks < 8; ++ks) {
        const unsigned short* abase =
            (ks < 4 ? rowa + ks * 32 : rowx + (ks - 4) * 32) + kg * 8;
        bf16x8 a = *reinterpret_cast<const bf16x8*>(abase);
        const unsigned short* wbase = Wp1 + ks * 4096 + lo16 * 32 + kg * 8;
#pragma unroll
        for (int n = 0; n < 8; ++n) {
            bf16x8 b = *reinterpret_cast<const bf16x8*>(wbase + n * 512);
            acc[n] = __builtin_amdgcn_mfma_f32_16x16x32_bf16(a, b, acc[n], 0, 0, 0);
        }
    }

    int r0 = (lane >> 4) * 4;
#pragma unroll
    for (int n = 0; n < 8; ++n) {
        int col = n * 16 + lo16;
        float bv = b1[col];
#pragma unroll
        for (int r = 0; r < 4; ++r) {
            int row = m0 + r0 + r;
            float v = acc[n][r] + bv;
            hbf[(size_t)row * 128 + col] = bf16r(fmaxf(v, 0.0f));
        }
    }
}

// ---- MFMA gemm2: [p | out] = h @ Wp2 (+b2 on right half) ; M=50000 K=128 N=128 ----
__global__ __launch_bounds__(256) void gemm2_kernel(const unsigned short* __restrict__ hbf,
                                                    const unsigned short* __restrict__ Wp2,
                                                    const float* __restrict__ b2,
                                                    unsigned short* __restrict__ pbf,
                                                    float* __restrict__ out) {
    int tile = blockIdx.x * 4 + (threadIdx.x >> 6);
    if (tile >= M_TILES) return;
    int lane = threadIdx.x & 63;
    int lo16 = lane & 15;
    int kg = lane >> 4;
    int m0 = tile * 16;

    f32x4 acc[8];
#pragma unroll
    for (int n = 0; n < 8; ++n) acc[n] = (f32x4){0.f, 0.f, 0.f, 0.f};

    const unsigned short* rowh = hbf + (size_t)(m0 + lo16) * 128;

#pragma unroll
    for (int ks = 0; ks < 4; ++ks) {
        bf16x8 a = *reinterpret_cast<const bf16x8*>(rowh + ks * 32 + kg * 8);
        const unsigned short* wbase = Wp2 + ks * 4096 + lo16 * 32 + kg * 8;
#pragma unroll
        for (int n = 0; n < 8; ++n) {
            bf16x8 b = *reinterpret_cast<const bf16x8*>(wbase + n * 512);
            acc[n] = __builtin_amdgcn_mfma_f32_16x16x32_bf16(a, b, acc[n], 0, 0, 0);
        }
    }

    int r0 = (lane >> 4) * 4;
#pragma unroll
    for (int n = 0; n < 8; ++n) {
        int col = n * 16 + lo16;
        if (col < 64) {
#pragma unroll
            for (int r = 0; r < 4; ++r) {
                int row = m0 + r0 + r;
                pbf[(size_t)row * 64 + col] = bf16r(acc[n][r]);
            }
        } else {
            float bv = b2[col - 64];
#pragma unroll
            for (int r = 0; r < 4; ++r) {
                int row = m0 + r0 + r;
                out[(size_t)row * 64 + (col - 64)] = acc[n][r] + bv;
            }
        }
    }
}

// ---- layer-2 gather: out[d] += invdeg[d] * sum p_bf[s]
//      2 edges/iteration: half-wave per edge, uint (2 feats) per lane ----
__global__ __launch_bounds__(64) void gather2_kernel(const int* __restrict__ off,
                                                     const int* __restrict__ ebuf,
                                                     const float* __restrict__ invdeg,
                                                     const unsigned* __restrict__ pbf,
                                                     float* __restrict__ out) {
    int d = blockIdx.x;
    int j = threadIdx.x;       // 0..63
    int half = j >> 5;         // which edge of a pair
    int f = j & 31;            // uint index within the 64-feat row
    int lo = off[d], hi = off[d + 1];
    float a0 = 0.0f, a1 = 0.0f;
    for (int i = lo + half; i < hi; i += 2) {
        unsigned v = pbf[(size_t)ebuf[i] * 32 + f];
        a0 += __uint_as_float(v << 16);
        a1 += __uint_as_float(v & 0xffff0000u);
    }
    a0 += __shfl_xor(a0, 32, 64);
    a1 += __shfl_xor(a1, 32, 64);
    if (half == 0) {
        float inv = invdeg[d];
        float2* op = (float2*)(out + (size_t)d * 64 + f * 2);
        float2 o = *op;
        o.x += a0 * inv;
        o.y += a1 * inv;
        *op = o;
    }
}

extern "C" void kernel_launch(void* const* d_in, const int* in_sizes, int n_in,
                              void* d_out, int out_size, void* d_ws, size_t ws_size,
                              hipStream_t stream) {
    const float* x   = (const float*)d_in[0];
    const int*   ei  = (const int*)d_in[1];
    const float* Wl1 = (const float*)d_in[2];
    const float* b1  = (const float*)d_in[3];
    const float* Wr1 = (const float*)d_in[4];
    const float* Wl2 = (const float*)d_in[5];
    const float* b2  = (const float*)d_in[6];
    const float* Wr2 = (const float*)d_in[7];
    float* out = (float*)d_out;

    const int E = in_sizes[1] / 2;
    const int* src = ei;
    const int* dst = ei + E;

    char* ws = (char*)d_ws;
    int*            off    = (int*)(ws + OFF_OFF);
    int*            cur    = (int*)(ws + CUR_OFF);
    int*            ebuf   = (int*)(ws + EBUF_OFF);
    int*            cnt    = (int*)(ws + CNT_OFF);
    float*          invdeg = (float*)(ws + INV_OFF);
    unsigned*       xbf    = (unsigned*)(ws + XBF_OFF);
    unsigned*       aggbf  = (unsigned*)(ws + AGG_OFF);
    unsigned short* hbf    = (unsigned short*)(ws + HBF_OFF);
    unsigned short* pbf    = (unsigned short*)(ws + PBF_OFF);
    int*            bsum   = (int*)(ws + PBF_OFF);   // borrowed before gemm2 writes pbf
    unsigned short* Wp1    = (unsigned short*)(ws + WP1_OFF);
    unsigned short* Wp2    = (unsigned short*)(ws + WP2_OFF);

    (void)hipMemsetAsync(cnt, 0, N_NODES * sizeof(int), stream);

    conv_kernel<<<(N_NODES * 32 + 255) / 256, 256, 0, stream>>>((const float4*)x, (uint2*)xbf,
                                                                N_NODES * 32);
    pack1_kernel<<<128, 256, 0, stream>>>(Wl1, Wr1, Wp1);
    pack2_kernel<<<64, 256, 0, stream>>>(Wl2, Wr2, Wp2);

    hist_kernel<<<(E + 255) / 256, 256, 0, stream>>>(dst, cnt, E);
    scanA_kernel<<<SCAN_BLOCKS, 256, 0, stream>>>(cnt, bsum);
    scanB_kernel<<<1, 256, 0, stream>>>(bsum, SCAN_BLOCKS);
    scanC_kernel<<<SCAN_BLOCKS, 256, 0, stream>>>(cnt, bsum, off, cur, invdeg);
    bucket_kernel<<<(E + 255) / 256, 256, 0, stream>>>(src, dst, cur, ebuf, E);

    // layer 1
    gather1_kernel<<<N_NODES, 64, 0, stream>>>(off, ebuf, invdeg, xbf, aggbf);
    gemm1_kernel<<<(M_TILES + 3) / 4, 256, 0, stream>>>((const unsigned short*)aggbf,
                                                        (const unsigned short*)xbf, Wp1, b1, hbf);

    // layer 2 (project-then-aggregate)
    gemm2_kernel<<<(M_TILES + 3) / 4, 256, 0, stream>>>(hbf, Wp2, b2, pbf, out);
    gather2_kernel<<<N_NODES, 64, 0, stream>>>(off, ebuf, invdeg, (const unsigned*)pbf, out);
}

// Round 6
// 200.052 us; speedup vs baseline: 11.1985x; 1.2086x over previous
//
#include <hip/hip_runtime.h>
#include <hip/hip_bf16.h>

#define N_NODES 50000
#define M_TILES 3125   // 50000/16
#define SCAN_BLOCKS ((N_NODES + 255) / 256)   // 196

typedef __attribute__((ext_vector_type(8))) __bf16 bf16x8;
typedef __attribute__((ext_vector_type(4))) float f32x4;

// ---------------- workspace layout (bytes) ----------------
#define OFF_OFF   0            // off:  50001 int
#define CUR_OFF   200192      // cur:  50000 int
#define EBUF_OFF  400384      // ebuf: 800000 int
#define CNT_OFF   3600384     // cnt:  50000 int
#define INV_OFF   3800576     // invdeg: 50000 f32
#define XBF_OFF   4000768     // x_bf:   50000x128 bf16 (12.8 MB)
#define AGG_OFF   16800768    // agg_bf: 50000x128 bf16
#define HBF_OFF   29600768    // h_bf:   50000x128 bf16
#define PBF_OFF   42400768    // p_bf:   50000x64  bf16 (6.4 MB); bsum borrows this early
#define WP1_OFF   48800768    // Wp1: 256x128 bf16 (64 KB)
#define WP2_OFF   48866304    // Wp2: 128x128 bf16 (32 KB)

// float -> bf16 bits (RNE), returned in high 16
__device__ __forceinline__ unsigned bfbits(float f) {
    unsigned u = __float_as_uint(f);
    return (u + 0x7fffu + ((u >> 16) & 1u)) & 0xffff0000u;
}
__device__ __forceinline__ unsigned short bf16r(float f) {
    return (unsigned short)(bfbits(f) >> 16);
}
__device__ __forceinline__ float blo(unsigned u) { return __uint_as_float(u << 16); }
__device__ __forceinline__ float bhi(unsigned u) { return __uint_as_float(u & 0xffff0000u); }

// ---- x (f32) -> x_bf ; also zeroes cnt (grid covers N_NODES) ----
__global__ __launch_bounds__(256) void conv_kernel(const float4* __restrict__ x4,
                                                   uint2* __restrict__ xbf,
                                                   int* __restrict__ cnt, int n4) {
    int i = blockIdx.x * 256 + threadIdx.x;
    if (i < N_NODES) cnt[i] = 0;
    if (i >= n4) return;
    float4 v = x4[i];
    uint2 o;
    o.x = (bfbits(v.x) >> 16) | bfbits(v.y);
    o.y = (bfbits(v.z) >> 16) | bfbits(v.w);
    xbf[i] = o;
}

// ---- pack both W into B-fragment layout: Wp[((k/32)*128 + n)*32 + ((k>>3)&3)*8 + (k&7)] ----
__global__ __launch_bounds__(256) void pack12_kernel(const float* __restrict__ Wl1,
                                                     const float* __restrict__ Wr1,
                                                     const float* __restrict__ Wl2,
                                                     const float* __restrict__ Wr2,
                                                     unsigned short* __restrict__ Wp1,
                                                     unsigned short* __restrict__ Wp2) {
    int b = blockIdx.x;
    if (b < 128) {
        int idx = b * 256 + threadIdx.x;  // 256*128
        int k = idx >> 7, n = idx & 127;
        float v = (k < 128) ? Wl1[k * 128 + n] : Wr1[(k - 128) * 128 + n];
        Wp1[((k >> 5) << 12) + (n << 5) + (((k >> 3) & 3) << 3) + (k & 7)] = bf16r(v);
    } else {
        int idx = (b - 128) * 256 + threadIdx.x;  // 128*128
        int k = idx >> 7, n = idx & 127;
        float v = (n < 64) ? Wl2[k * 64 + n] : Wr2[k * 64 + (n - 64)];
        Wp2[((k >> 5) << 12) + (n << 5) + (((k >> 3) & 3) << 3) + (k & 7)] = bf16r(v);
    }
}

// ---- degree histogram ----
__global__ __launch_bounds__(256) void hist_kernel(const int* __restrict__ dst,
                                                   int* __restrict__ cnt, int E) {
    int e = blockIdx.x * 256 + threadIdx.x;
    if (e < E) atomicAdd(&cnt[dst[e]], 1);
}

// ---- scan phase A: per-block (256 nodes) sums ----
__global__ __launch_bounds__(256) void scanA_kernel(const int* __restrict__ cnt,
                                                    int* __restrict__ bsum) {
    __shared__ int sm[4];
    int i = blockIdx.x * 256 + threadIdx.x;
    int v = (i < N_NODES) ? cnt[i] : 0;
    for (int d = 32; d; d >>= 1) v += __shfl_down(v, d, 64);
    if ((threadIdx.x & 63) == 0) sm[threadIdx.x >> 6] = v;
    __syncthreads();
    if (threadIdx.x == 0) bsum[blockIdx.x] = sm[0] + sm[1] + sm[2] + sm[3];
}

// ---- scan phase B: exclusive scan of 196 block sums ----
__global__ __launch_bounds__(256) void scanB_kernel(int* __restrict__ bsum, int nb) {
    __shared__ int sm[256];
    int t = threadIdx.x;
    int v = (t < nb) ? bsum[t] : 0;
    sm[t] = v;
    __syncthreads();
    for (int d = 1; d < 256; d <<= 1) {
        int u = (t >= d) ? sm[t - d] : 0;
        __syncthreads();
        sm[t] += u;
        __syncthreads();
    }
    if (t < nb) bsum[t] = sm[t] - v;  // exclusive
}

// ---- scan phase C: per-block exclusive rescan + global offset -> off, cur, invdeg ----
__global__ __launch_bounds__(256) void scanC_kernel(const int* __restrict__ cnt,
                                                    const int* __restrict__ bsum,
                                                    int* __restrict__ off,
                                                    int* __restrict__ cur,
                                                    float* __restrict__ invdeg) {
    __shared__ int sm[256];
    int t = threadIdx.x;
    int i = blockIdx.x * 256 + t;
    int c = (i < N_NODES) ? cnt[i] : 0;
    sm[t] = c;
    __syncthreads();
    for (int d = 1; d < 256; d <<= 1) {
        int u = (t >= d) ? sm[t - d] : 0;
        __syncthreads();
        sm[t] += u;
        __syncthreads();
    }
    int excl = sm[t] - c + bsum[blockIdx.x];
    if (i < N_NODES) {
        off[i] = excl;
        cur[i] = excl;
        invdeg[i] = 1.0f / fmaxf((float)c, 1.0f);
        if (i == N_NODES - 1) off[N_NODES] = excl + c;
    }
}

// ---- bucket fill (dst-CSR) ----
__global__ __launch_bounds__(256) void bucket_kernel(const int* __restrict__ src,
                                                     const int* __restrict__ dst,
                                                     int* __restrict__ cur,
                                                     int* __restrict__ ebuf, int E) {
    int e = blockIdx.x * 256 + threadIdx.x;
    if (e < E) {
        int pos = atomicAdd(&cur[dst[e]], 1);
        ebuf[pos] = src[e];
    }
}

// ---- layer-1 gather: 4 edges/iter, 16 lanes/edge, uint4 (8 feats) per lane ----
__global__ __launch_bounds__(64) void gather1_kernel(const int* __restrict__ off,
                                                     const int* __restrict__ ebuf,
                                                     const float* __restrict__ invdeg,
                                                     const uint4* __restrict__ xbf4,
                                                     uint4* __restrict__ aggbf4) {
    int d = blockIdx.x;
    int j = threadIdx.x;
    int g = j >> 4;    // edge group 0..3
    int f = j & 15;    // uint4 index within 256B row
    int lo = off[d], hi = off[d + 1];
    float a[8] = {0.f, 0.f, 0.f, 0.f, 0.f, 0.f, 0.f, 0.f};
    for (int i = lo + g; i < hi; i += 4) {
        int s = ebuf[i];
        uint4 v = xbf4[(size_t)s * 16 + f];
        a[0] += blo(v.x); a[1] += bhi(v.x);
        a[2] += blo(v.y); a[3] += bhi(v.y);
        a[4] += blo(v.z); a[5] += bhi(v.z);
        a[6] += blo(v.w); a[7] += bhi(v.w);
    }
#pragma unroll
    for (int q = 0; q < 8; ++q) {
        a[q] += __shfl_xor(a[q], 16, 64);
        a[q] += __shfl_xor(a[q], 32, 64);
    }
    if (g == 0) {
        float inv = invdeg[d];
        uint4 o;
        o.x = (bfbits(a[0] * inv) >> 16) | bfbits(a[1] * inv);
        o.y = (bfbits(a[2] * inv) >> 16) | bfbits(a[3] * inv);
        o.z = (bfbits(a[4] * inv) >> 16) | bfbits(a[5] * inv);
        o.w = (bfbits(a[6] * inv) >> 16) | bfbits(a[7] * inv);
        aggbf4[(size_t)d * 16 + f] = o;
    }
}

// ---- MFMA gemm1: h = relu([agg|x] @ Wp1 + b1) ; M=50000 K=256 N=128 ----
__global__ __launch_bounds__(256) void gemm1_kernel(const unsigned short* __restrict__ aggbf,
                                                    const unsigned short* __restrict__ xbf,
                                                    const unsigned short* __restrict__ Wp1,
                                                    const float* __restrict__ b1,
                                                    unsigned short* __restrict__ hbf) {
    int tile = blockIdx.x * 4 + (threadIdx.x >> 6);
    if (tile >= M_TILES) return;
    int lane = threadIdx.x & 63;
    int lo16 = lane & 15;
    int kg = lane >> 4;
    int m0 = tile * 16;

    f32x4 acc[8];
#pragma unroll
    for (int n = 0; n < 8; ++n) acc[n] = (f32x4){0.f, 0.f, 0.f, 0.f};

    int arow = m0 + lo16;
    const unsigned short* rowa = aggbf + (size_t)arow * 128;
    const unsigned short* rowx = xbf + (size_t)arow * 128;

#pragma unroll
    for (int ks = 0; ks < 8; ++ks) {
        const unsigned short* abase =
            (ks < 4 ? rowa + ks * 32 : rowx + (ks - 4) * 32) + kg * 8;
        bf16x8 a = *reinterpret_cast<const bf16x8*>(abase);
        const unsigned short* wbase = Wp1 + ks * 4096 + lo16 * 32 + kg * 8;
#pragma unroll
        for (int n = 0; n < 8; ++n) {
            bf16x8 b = *reinterpret_cast<const bf16x8*>(wbase + n * 512);
            acc[n] = __builtin_amdgcn_mfma_f32_16x16x32_bf16(a, b, acc[n], 0, 0, 0);
        }
    }

    int r0 = (lane >> 4) * 4;
#pragma unroll
    for (int n = 0; n < 8; ++n) {
        int col = n * 16 + lo16;
        float bv = b1[col];
#pragma unroll
        for (int r = 0; r < 4; ++r) {
            int row = m0 + r0 + r;
            float v = acc[n][r] + bv;
            hbf[(size_t)row * 128 + col] = bf16r(fmaxf(v, 0.0f));
        }
    }
}

// ---- MFMA gemm2: [p | out] = h @ Wp2 (+b2 on right half) ; M=50000 K=128 N=128 ----
__global__ __launch_bounds__(256) void gemm2_kernel(const unsigned short* __restrict__ hbf,
                                                    const unsigned short* __restrict__ Wp2,
                                                    const float* __restrict__ b2,
                                                    unsigned short* __restrict__ pbf,
                                                    float* __restrict__ out) {
    int tile = blockIdx.x * 4 + (threadIdx.x >> 6);
    if (tile >= M_TILES) return;
    int lane = threadIdx.x & 63;
    int lo16 = lane & 15;
    int kg = lane >> 4;
    int m0 = tile * 16;

    f32x4 acc[8];
#pragma unroll
    for (int n = 0; n < 8; ++n) acc[n] = (f32x4){0.f, 0.f, 0.f, 0.f};

    const unsigned short* rowh = hbf + (size_t)(m0 + lo16) * 128;

#pragma unroll
    for (int ks = 0; ks < 4; ++ks) {
        bf16x8 a = *reinterpret_cast<const bf16x8*>(rowh + ks * 32 + kg * 8);
        const unsigned short* wbase = Wp2 + ks * 4096 + lo16 * 32 + kg * 8;
#pragma unroll
        for (int n = 0; n < 8; ++n) {
            bf16x8 b = *reinterpret_cast<const bf16x8*>(wbase + n * 512);
            acc[n] = __builtin_amdgcn_mfma_f32_16x16x32_bf16(a, b, acc[n], 0, 0, 0);
        }
    }

    int r0 = (lane >> 4) * 4;
#pragma unroll
    for (int n = 0; n < 8; ++n) {
        int col = n * 16 + lo16;
        if (col < 64) {
#pragma unroll
            for (int r = 0; r < 4; ++r) {
                int row = m0 + r0 + r;
                pbf[(size_t)row * 64 + col] = bf16r(acc[n][r]);
            }
        } else {
            float bv = b2[col - 64];
#pragma unroll
            for (int r = 0; r < 4; ++r) {
                int row = m0 + r0 + r;
                out[(size_t)row * 64 + (col - 64)] = acc[n][r] + bv;
            }
        }
    }
}

// ---- layer-2 gather: 4 edges/iter, 16 lanes/edge, uint2 (4 feats) per lane ----
__global__ __launch_bounds__(64) void gather2_kernel(const int* __restrict__ off,
                                                     const int* __restrict__ ebuf,
                                                     const float* __restrict__ invdeg,
                                                     const uint2* __restrict__ pbf2,
                                                     float4* __restrict__ out4) {
    int d = blockIdx.x;
    int j = threadIdx.x;
    int g = j >> 4;    // edge group 0..3
    int f = j & 15;    // uint2 index within 128B row
    int lo = off[d], hi = off[d + 1];
    float a0 = 0.f, a1 = 0.f, a2 = 0.f, a3 = 0.f;
    for (int i = lo + g; i < hi; i += 4) {
        int s = ebuf[i];
        uint2 v = pbf2[(size_t)s * 16 + f];
        a0 += blo(v.x); a1 += bhi(v.x);
        a2 += blo(v.y); a3 += bhi(v.y);
    }
    a0 += __shfl_xor(a0, 16, 64); a0 += __shfl_xor(a0, 32, 64);
    a1 += __shfl_xor(a1, 16, 64); a1 += __shfl_xor(a1, 32, 64);
    a2 += __shfl_xor(a2, 16, 64); a2 += __shfl_xor(a2, 32, 64);
    a3 += __shfl_xor(a3, 16, 64); a3 += __shfl_xor(a3, 32, 64);
    if (g == 0) {
        float inv = invdeg[d];
        float4* op = out4 + (size_t)d * 16 + f;
        float4 o = *op;
        o.x += a0 * inv;
        o.y += a1 * inv;
        o.z += a2 * inv;
        o.w += a3 * inv;
        *op = o;
    }
}

extern "C" void kernel_launch(void* const* d_in, const int* in_sizes, int n_in,
                              void* d_out, int out_size, void* d_ws, size_t ws_size,
                              hipStream_t stream) {
    const float* x   = (const float*)d_in[0];
    const int*   ei  = (const int*)d_in[1];
    const float* Wl1 = (const float*)d_in[2];
    const float* b1  = (const float*)d_in[3];
    const float* Wr1 = (const float*)d_in[4];
    const float* Wl2 = (const float*)d_in[5];
    const float* b2  = (const float*)d_in[6];
    const float* Wr2 = (const float*)d_in[7];
    float* out = (float*)d_out;

    const int E = in_sizes[1] / 2;
    const int* src = ei;
    const int* dst = ei + E;

    char* ws = (char*)d_ws;
    int*            off    = (int*)(ws + OFF_OFF);
    int*            cur    = (int*)(ws + CUR_OFF);
    int*            ebuf   = (int*)(ws + EBUF_OFF);
    int*            cnt    = (int*)(ws + CNT_OFF);
    float*          invdeg = (float*)(ws + INV_OFF);
    unsigned*       xbf    = (unsigned*)(ws + XBF_OFF);
    unsigned*       aggbf  = (unsigned*)(ws + AGG_OFF);
    unsigned short* hbf    = (unsigned short*)(ws + HBF_OFF);
    unsigned short* pbf    = (unsigned short*)(ws + PBF_OFF);
    int*            bsum   = (int*)(ws + PBF_OFF);   // borrowed before gemm2 writes pbf
    unsigned short* Wp1    = (unsigned short*)(ws + WP1_OFF);
    unsigned short* Wp2    = (unsigned short*)(ws + WP2_OFF);

    conv_kernel<<<(N_NODES * 32 + 255) / 256, 256, 0, stream>>>((const float4*)x, (uint2*)xbf,
                                                                cnt, N_NODES * 32);
    pack12_kernel<<<192, 256, 0, stream>>>(Wl1, Wr1, Wl2, Wr2, Wp1, Wp2);

    hist_kernel<<<(E + 255) / 256, 256, 0, stream>>>(dst, cnt, E);
    scanA_kernel<<<SCAN_BLOCKS, 256, 0, stream>>>(cnt, bsum);
    scanB_kernel<<<1, 256, 0, stream>>>(bsum, SCAN_BLOCKS);
    scanC_kernel<<<SCAN_BLOCKS, 256, 0, stream>>>(cnt, bsum, off, cur, invdeg);
    bucket_kernel<<<(E + 255) / 256, 256, 0, stream>>>(src, dst, cur, ebuf, E);

    // layer 1
    gather1_kernel<<<N_NODES, 64, 0, stream>>>(off, ebuf, invdeg, (const uint4*)xbf,
                                               (uint4*)aggbf);
    gemm1_kernel<<<(M_TILES + 3) / 4, 256, 0, stream>>>((const unsigned short*)aggbf,
                                                        (const unsigned short*)xbf, Wp1, b1, hbf);

    // layer 2 (project-then-aggregate)
    gemm2_kernel<<<(M_TILES + 3) / 4, 256, 0, stream>>>(hbf, Wp2, b2, pbf, out);
    gather2_kernel<<<N_NODES, 64, 0, stream>>>(off, ebuf, invdeg, (const uint2*)pbf,
                                               (float4*)out);
}

// Round 7
// 174.607 us; speedup vs baseline: 12.8304x; 1.1457x over previous
//
#include <hip/hip_runtime.h>
#include <hip/hip_bf16.h>

#define N_NODES 50000
#define M_TILES 3125   // 50000/16
#define SCAN_BLOCKS ((N_NODES + 255) / 256)   // 196 == number of coarse buckets
#define CHUNK_A 3125   // edges per passA block (800000/256)
#define PASSB_CAP 12288

typedef __attribute__((ext_vector_type(8))) __bf16 bf16x8;
typedef __attribute__((ext_vector_type(4))) float f32x4;

// ---------------- workspace layout (bytes) ----------------
#define OFF_OFF   0            // off:  50001 int
#define CUR_OFF   200192      // cur:  50000 int (fallback cursors)
#define EBUF_OFF  400384      // ebuf: 800000 ushort (1.6 MB)
#define GCUR_OFF  2000384     // gcur: 196 int (coarse bucket cursors)
#define CNT_OFF   3600384     // cnt:  50000 int
#define INV_OFF   3800576     // invdeg: 50000 f32
#define XBF_OFF   4000768     // x_bf:   50000x128 bf16 (12.8 MB)
#define AGG_OFF   16800768    // agg_bf: 50000x128 bf16
#define HBF_OFF   29600768    // h_bf: 50000x128 bf16; pairs (3.2 MB) borrows this early
#define PBF_OFF   42400768    // p_bf: 50000x64 bf16; bsum borrows this early
#define WP1_OFF   48800768    // Wp1: 256x128 bf16 (64 KB)
#define WP2_OFF   48866304    // Wp2: 128x128 bf16 (32 KB)

// float -> bf16 bits (RNE), returned in high 16
__device__ __forceinline__ unsigned bfbits(float f) {
    unsigned u = __float_as_uint(f);
    return (u + 0x7fffu + ((u >> 16) & 1u)) & 0xffff0000u;
}
__device__ __forceinline__ unsigned short bf16r(float f) {
    return (unsigned short)(bfbits(f) >> 16);
}
__device__ __forceinline__ float blo(unsigned u) { return __uint_as_float(u << 16); }
__device__ __forceinline__ float bhi(unsigned u) { return __uint_as_float(u & 0xffff0000u); }

// ---- x (f32) -> x_bf ; also zeroes cnt ----
__global__ __launch_bounds__(256) void conv_kernel(const float4* __restrict__ x4,
                                                   uint2* __restrict__ xbf,
                                                   int* __restrict__ cnt, int n4) {
    int i = blockIdx.x * 256 + threadIdx.x;
    if (i < N_NODES) cnt[i] = 0;
    if (i >= n4) return;
    float4 v = x4[i];
    uint2 o;
    o.x = (bfbits(v.x) >> 16) | bfbits(v.y);
    o.y = (bfbits(v.z) >> 16) | bfbits(v.w);
    xbf[i] = o;
}

// ---- pack both W into B-fragment layout ----
__global__ __launch_bounds__(256) void pack12_kernel(const float* __restrict__ Wl1,
                                                     const float* __restrict__ Wr1,
                                                     const float* __restrict__ Wl2,
                                                     const float* __restrict__ Wr2,
                                                     unsigned short* __restrict__ Wp1,
                                                     unsigned short* __restrict__ Wp2) {
    int b = blockIdx.x;
    if (b < 128) {
        int idx = b * 256 + threadIdx.x;
        int k = idx >> 7, n = idx & 127;
        float v = (k < 128) ? Wl1[k * 128 + n] : Wr1[(k - 128) * 128 + n];
        Wp1[((k >> 5) << 12) + (n << 5) + (((k >> 3) & 3) << 3) + (k & 7)] = bf16r(v);
    } else {
        int idx = (b - 128) * 256 + threadIdx.x;
        int k = idx >> 7, n = idx & 127;
        float v = (n < 64) ? Wl2[k * 64 + n] : Wr2[k * 64 + (n - 64)];
        Wp2[((k >> 5) << 12) + (n << 5) + (((k >> 3) & 3) << 3) + (k & 7)] = bf16r(v);
    }
}

// ---- degree histogram ----
__global__ __launch_bounds__(256) void hist_kernel(const int* __restrict__ dst,
                                                   int* __restrict__ cnt, int E) {
    int e = blockIdx.x * 256 + threadIdx.x;
    if (e < E) atomicAdd(&cnt[dst[e]], 1);
}

// ---- scan phase A: per-block (256 nodes) sums ----
__global__ __launch_bounds__(256) void scanA_kernel(const int* __restrict__ cnt,
                                                    int* __restrict__ bsum) {
    __shared__ int sm[4];
    int i = blockIdx.x * 256 + threadIdx.x;
    int v = (i < N_NODES) ? cnt[i] : 0;
    for (int d = 32; d; d >>= 1) v += __shfl_down(v, d, 64);
    if ((threadIdx.x & 63) == 0) sm[threadIdx.x >> 6] = v;
    __syncthreads();
    if (threadIdx.x == 0) bsum[blockIdx.x] = sm[0] + sm[1] + sm[2] + sm[3];
}

// ---- scan phase B: exclusive scan of 196 block sums ----
__global__ __launch_bounds__(256) void scanB_kernel(int* __restrict__ bsum, int nb) {
    __shared__ int sm[256];
    int t = threadIdx.x;
    int v = (t < nb) ? bsum[t] : 0;
    sm[t] = v;
    __syncthreads();
    for (int d = 1; d < 256; d <<= 1) {
        int u = (t >= d) ? sm[t - d] : 0;
        __syncthreads();
        sm[t] += u;
        __syncthreads();
    }
    if (t < nb) bsum[t] = sm[t] - v;  // exclusive
}

// ---- scan phase C: off/cur/invdeg + coarse cursors gcur[b]=off[b*256] ----
__global__ __launch_bounds__(256) void scanC_kernel(const int* __restrict__ cnt,
                                                    const int* __restrict__ bsum,
                                                    int* __restrict__ off,
                                                    int* __restrict__ cur,
                                                    int* __restrict__ gcur,
                                                    float* __restrict__ invdeg) {
    __shared__ int sm[256];
    int t = threadIdx.x;
    int i = blockIdx.x * 256 + t;
    int c = (i < N_NODES) ? cnt[i] : 0;
    sm[t] = c;
    __syncthreads();
    for (int d = 1; d < 256; d <<= 1) {
        int u = (t >= d) ? sm[t - d] : 0;
        __syncthreads();
        sm[t] += u;
        __syncthreads();
    }
    int excl = sm[t] - c + bsum[blockIdx.x];
    if (t == 0) gcur[blockIdx.x] = bsum[blockIdx.x];  // == off[block*256]
    if (i < N_NODES) {
        off[i] = excl;
        cur[i] = excl;
        invdeg[i] = 1.0f / fmaxf((float)c, 1.0f);
        if (i == N_NODES - 1) off[N_NODES] = excl + c;
    }
}

// ---- pass A: coarse partition into 196 buckets, LDS-compacted dense writes ----
__global__ __launch_bounds__(256) void passA_kernel(const int* __restrict__ src,
                                                    const int* __restrict__ dst,
                                                    int* __restrict__ gcur,
                                                    unsigned* __restrict__ pairs, int E) {
    __shared__ int bh[256];    // hist -> exclusive base
    __shared__ int lcur[256];
    __shared__ int gb[256];
    __shared__ int sc[256];
    __shared__ unsigned lbuf[3328];
    int t = threadIdx.x;
    int e0 = blockIdx.x * CHUNK_A;
    int e1 = min(e0 + CHUNK_A, E);
    bh[t] = 0;
    lcur[t] = 0;
    __syncthreads();
    for (int e = e0 + t; e < e1; e += 256) atomicAdd(&bh[dst[e] >> 8], 1);
    __syncthreads();
    int v = bh[t];
    sc[t] = v;
    __syncthreads();
    for (int d = 1; d < 256; d <<= 1) {
        int u = (t >= d) ? sc[t - d] : 0;
        __syncthreads();
        sc[t] += u;
        __syncthreads();
    }
    int lbase = sc[t] - v;
    if (v > 0) gb[t] = atomicAdd(&gcur[t], v);  // claim contiguous run in bucket t
    bh[t] = lbase;
    __syncthreads();
    for (int e = e0 + t; e < e1; e += 256) {
        int s = src[e], d = dst[e];
        int b = d >> 8;
        int lpos = bh[b] + atomicAdd(&lcur[b], 1);
        lbuf[lpos] = (unsigned)s | ((unsigned)d << 16);
    }
    __syncthreads();
    int T = e1 - e0;
    for (int k = t; k < T; k += 256) {
        unsigned p = lbuf[k];
        int b = p >> 24;
        pairs[gb[b] + (k - bh[b])] = p;
    }
}

// ---- pass B: fine order within each coarse bucket, dense ushort ebuf write ----
__global__ __launch_bounds__(256) void passB_kernel(const int* __restrict__ off,
                                                    const unsigned* __restrict__ pairs,
                                                    int* __restrict__ cur,
                                                    unsigned short* __restrict__ ebuf16) {
    __shared__ int lcnt[256];
    __shared__ unsigned short lout[PASSB_CAP];
    int b = blockIdx.x;
    int dbase = b * 256;
    int t = threadIdx.x;
    int winlo = off[dbase];
    int dtop = min(dbase + 256, N_NODES);
    int winhi = off[dtop];
    int W = winhi - winlo;
    int d_g = dbase + t;
    lcnt[t] = (d_g < N_NODES) ? off[d_g] - winlo : 0;
    __syncthreads();
    if (W <= PASSB_CAP) {
        for (int k = t; k < W; k += 256) {
            unsigned p = pairs[winlo + k];
            int dl = (p >> 16) - dbase;
            int pos = atomicAdd(&lcnt[dl], 1);
            lout[pos] = (unsigned short)(p & 0xffffu);
        }
        __syncthreads();
        for (int k = t; k < W; k += 256) ebuf16[winlo + k] = lout[k];
    } else {  // fallback (never for this input): global-cursor scatter
        for (int k = t; k < W; k += 256) {
            unsigned p = pairs[winlo + k];
            int d = (int)(p >> 16);
            int pos = atomicAdd(&cur[d], 1);
            ebuf16[pos] = (unsigned short)(p & 0xffffu);
        }
    }
}

// ---- layer-1 gather: 4 edges/iter, 16 lanes/edge, uint4 (8 feats) per lane ----
__global__ __launch_bounds__(64) void gather1_kernel(const int* __restrict__ off,
                                                     const unsigned short* __restrict__ ebuf,
                                                     const float* __restrict__ invdeg,
                                                     const uint4* __restrict__ xbf4,
                                                     uint4* __restrict__ aggbf4) {
    int d = blockIdx.x;
    int j = threadIdx.x;
    int g = j >> 4;
    int f = j & 15;
    int lo = off[d], hi = off[d + 1];
    float a[8] = {0.f, 0.f, 0.f, 0.f, 0.f, 0.f, 0.f, 0.f};
    for (int i = lo + g; i < hi; i += 4) {
        int s = ebuf[i];
        uint4 v = xbf4[(size_t)s * 16 + f];
        a[0] += blo(v.x); a[1] += bhi(v.x);
        a[2] += blo(v.y); a[3] += bhi(v.y);
        a[4] += blo(v.z); a[5] += bhi(v.z);
        a[6] += blo(v.w); a[7] += bhi(v.w);
    }
#pragma unroll
    for (int q = 0; q < 8; ++q) {
        a[q] += __shfl_xor(a[q], 16, 64);
        a[q] += __shfl_xor(a[q], 32, 64);
    }
    if (g == 0) {
        float inv = invdeg[d];
        uint4 o;
        o.x = (bfbits(a[0] * inv) >> 16) | bfbits(a[1] * inv);
        o.y = (bfbits(a[2] * inv) >> 16) | bfbits(a[3] * inv);
        o.z = (bfbits(a[4] * inv) >> 16) | bfbits(a[5] * inv);
        o.w = (bfbits(a[6] * inv) >> 16) | bfbits(a[7] * inv);
        aggbf4[(size_t)d * 16 + f] = o;
    }
}

// ---- MFMA gemm1: h = relu([agg|x] @ Wp1 + b1) ; M=50000 K=256 N=128 ----
__global__ __launch_bounds__(256) void gemm1_kernel(const unsigned short* __restrict__ aggbf,
                                                    const unsigned short* __restrict__ xbf,
                                                    const unsigned short* __restrict__ Wp1,
                                                    const float* __restrict__ b1,
                                                    unsigned short* __restrict__ hbf) {
    int tile = blockIdx.x * 4 + (threadIdx.x >> 6);
    if (tile >= M_TILES) return;
    int lane = threadIdx.x & 63;
    int lo16 = lane & 15;
    int kg = lane >> 4;
    int m0 = tile * 16;

    f32x4 acc[8];
#pragma unroll
    for (int n = 0; n < 8; ++n) acc[n] = (f32x4){0.f, 0.f, 0.f, 0.f};

    int arow = m0 + lo16;
    const unsigned short* rowa = aggbf + (size_t)arow * 128;
    const unsigned short* rowx = xbf + (size_t)arow * 128;

#pragma unroll
    for (int ks = 0; ks < 8; ++ks) {
        const unsigned short* abase =
            (ks < 4 ? rowa + ks * 32 : rowx + (ks - 4) * 32) + kg * 8;
        bf16x8 a = *reinterpret_cast<const bf16x8*>(abase);
        const unsigned short* wbase = Wp1 + ks * 4096 + lo16 * 32 + kg * 8;
#pragma unroll
        for (int n = 0; n < 8; ++n) {
            bf16x8 b = *reinterpret_cast<const bf16x8*>(wbase + n * 512);
            acc[n] = __builtin_amdgcn_mfma_f32_16x16x32_bf16(a, b, acc[n], 0, 0, 0);
        }
    }

    int r0 = (lane >> 4) * 4;
#pragma unroll
    for (int n = 0; n < 8; ++n) {
        int col = n * 16 + lo16;
        float bv = b1[col];
#pragma unroll
        for (int r = 0; r < 4; ++r) {
            int row = m0 + r0 + r;
            float v = acc[n][r] + bv;
            hbf[(size_t)row * 128 + col] = bf16r(fmaxf(v, 0.0f));
        }
    }
}

// ---- MFMA gemm2: [p | out] = h @ Wp2 (+b2 on right half) ; M=50000 K=128 N=128 ----
__global__ __launch_bounds__(256) void gemm2_kernel(const unsigned short* __restrict__ hbf,
                                                    const unsigned short* __restrict__ Wp2,
                                                    const float* __restrict__ b2,
                                                    unsigned short* __restrict__ pbf,
                                                    float* __restrict__ out) {
    int tile = blockIdx.x * 4 + (threadIdx.x >> 6);
    if (tile >= M_TILES) return;
    int lane = threadIdx.x & 63;
    int lo16 = lane & 15;
    int kg = lane >> 4;
    int m0 = tile * 16;

    f32x4 acc[8];
#pragma unroll
    for (int n = 0; n < 8; ++n) acc[n] = (f32x4){0.f, 0.f, 0.f, 0.f};

    const unsigned short* rowh = hbf + (size_t)(m0 + lo16) * 128;

#pragma unroll
    for (int ks = 0; ks < 4; ++ks) {
        bf16x8 a = *reinterpret_cast<const bf16x8*>(rowh + ks * 32 + kg * 8);
        const unsigned short* wbase = Wp2 + ks * 4096 + lo16 * 32 + kg * 8;
#pragma unroll
        for (int n = 0; n < 8; ++n) {
            bf16x8 b = *reinterpret_cast<const bf16x8*>(wbase + n * 512);
            acc[n] = __builtin_amdgcn_mfma_f32_16x16x32_bf16(a, b, acc[n], 0, 0, 0);
        }
    }

    int r0 = (lane >> 4) * 4;
#pragma unroll
    for (int n = 0; n < 8; ++n) {
        int col = n * 16 + lo16;
        if (col < 64) {
#pragma unroll
            for (int r = 0; r < 4; ++r) {
                int row = m0 + r0 + r;
                pbf[(size_t)row * 64 + col] = bf16r(acc[n][r]);
            }
        } else {
            float bv = b2[col - 64];
#pragma unroll
            for (int r = 0; r < 4; ++r) {
                int row = m0 + r0 + r;
                out[(size_t)row * 64 + (col - 64)] = acc[n][r] + bv;
            }
        }
    }
}

// ---- layer-2 gather: 4 edges/iter, 16 lanes/edge, uint2 (4 feats) per lane ----
__global__ __launch_bounds__(64) void gather2_kernel(const int* __restrict__ off,
                                                     const unsigned short* __restrict__ ebuf,
                                                     const float* __restrict__ invdeg,
                                                     const uint2* __restrict__ pbf2,
                                                     float4* __restrict__ out4) {
    int d = blockIdx.x;
    int j = threadIdx.x;
    int g = j >> 4;
    int f = j & 15;
    int lo = off[d], hi = off[d + 1];
    float a0 = 0.f, a1 = 0.f, a2 = 0.f, a3 = 0.f;
    for (int i = lo + g; i < hi; i += 4) {
        int s = ebuf[i];
        uint2 v = pbf2[(size_t)s * 16 + f];
        a0 += blo(v.x); a1 += bhi(v.x);
        a2 += blo(v.y); a3 += bhi(v.y);
    }
    a0 += __shfl_xor(a0, 16, 64); a0 += __shfl_xor(a0, 32, 64);
    a1 += __shfl_xor(a1, 16, 64); a1 += __shfl_xor(a1, 32, 64);
    a2 += __shfl_xor(a2, 16, 64); a2 += __shfl_xor(a2, 32, 64);
    a3 += __shfl_xor(a3, 16, 64); a3 += __shfl_xor(a3, 32, 64);
    if (g == 0) {
        float inv = invdeg[d];
        float4* op = out4 + (size_t)d * 16 + f;
        float4 o = *op;
        o.x += a0 * inv;
        o.y += a1 * inv;
        o.z += a2 * inv;
        o.w += a3 * inv;
        *op = o;
    }
}

extern "C" void kernel_launch(void* const* d_in, const int* in_sizes, int n_in,
                              void* d_out, int out_size, void* d_ws, size_t ws_size,
                              hipStream_t stream) {
    const float* x   = (const float*)d_in[0];
    const int*   ei  = (const int*)d_in[1];
    const float* Wl1 = (const float*)d_in[2];
    const float* b1  = (const float*)d_in[3];
    const float* Wr1 = (const float*)d_in[4];
    const float* Wl2 = (const float*)d_in[5];
    const float* b2  = (const float*)d_in[6];
    const float* Wr2 = (const float*)d_in[7];
    float* out = (float*)d_out;

    const int E = in_sizes[1] / 2;
    const int* src = ei;
    const int* dst = ei + E;

    char* ws = (char*)d_ws;
    int*            off    = (int*)(ws + OFF_OFF);
    int*            cur    = (int*)(ws + CUR_OFF);
    unsigned short* ebuf16 = (unsigned short*)(ws + EBUF_OFF);
    int*            gcur   = (int*)(ws + GCUR_OFF);
    int*            cnt    = (int*)(ws + CNT_OFF);
    float*          invdeg = (float*)(ws + INV_OFF);
    unsigned*       xbf    = (unsigned*)(ws + XBF_OFF);
    unsigned*       aggbf  = (unsigned*)(ws + AGG_OFF);
    unsigned short* hbf    = (unsigned short*)(ws + HBF_OFF);
    unsigned*       pairs  = (unsigned*)(ws + HBF_OFF);   // borrowed before gemm1 writes hbf
    unsigned short* pbf    = (unsigned short*)(ws + PBF_OFF);
    int*            bsum   = (int*)(ws + PBF_OFF);        // borrowed before gemm2 writes pbf
    unsigned short* Wp1    = (unsigned short*)(ws + WP1_OFF);
    unsigned short* Wp2    = (unsigned short*)(ws + WP2_OFF);

    conv_kernel<<<(N_NODES * 32 + 255) / 256, 256, 0, stream>>>((const float4*)x, (uint2*)xbf,
                                                                cnt, N_NODES * 32);
    pack12_kernel<<<192, 256, 0, stream>>>(Wl1, Wr1, Wl2, Wr2, Wp1, Wp2);

    hist_kernel<<<(E + 255) / 256, 256, 0, stream>>>(dst, cnt, E);
    scanA_kernel<<<SCAN_BLOCKS, 256, 0, stream>>>(cnt, bsum);
    scanB_kernel<<<1, 256, 0, stream>>>(bsum, SCAN_BLOCKS);
    scanC_kernel<<<SCAN_BLOCKS, 256, 0, stream>>>(cnt, bsum, off, cur, gcur, invdeg);

    // dst-CSR build, write-dense two-phase partition
    passA_kernel<<<(E + CHUNK_A - 1) / CHUNK_A, 256, 0, stream>>>(src, dst, gcur, pairs, E);
    passB_kernel<<<SCAN_BLOCKS, 256, 0, stream>>>(off, pairs, cur, ebuf16);

    // layer 1
    gather1_kernel<<<N_NODES, 64, 0, stream>>>(off, ebuf16, invdeg, (const uint4*)xbf,
                                               (uint4*)aggbf);
    gemm1_kernel<<<(M_TILES + 3) / 4, 256, 0, stream>>>((const unsigned short*)aggbf,
                                                        (const unsigned short*)xbf, Wp1, b1, hbf);

    // layer 2 (project-then-aggregate)
    gemm2_kernel<<<(M_TILES + 3) / 4, 256, 0, stream>>>(hbf, Wp2, b2, pbf, out);
    gather2_kernel<<<N_NODES, 64, 0, stream>>>(off, ebuf16, invdeg, (const uint2*)pbf,
                                               (float4*)out);
}

// Round 8
// 132.419 us; speedup vs baseline: 16.9181x; 1.3186x over previous
//
#include <hip/hip_runtime.h>
#include <hip/hip_bf16.h>

#define N_NODES 50000
#define M_TILES 3125   // 50000/16
#define NBUCKET 196    // coarse buckets (dst>>8)
#define CHUNK_A 3125   // edges per passA/histC block
#define PASSB_CAP 12288
#define CONV_BLOCKS 6250   // N_NODES*32/256

typedef __attribute__((ext_vector_type(8))) __bf16 bf16x8;
typedef __attribute__((ext_vector_type(4))) float f32x4;

// ---------------- workspace layout (bytes) ----------------
#define OFF_OFF   0            // off:  50001 int
#define EBUF_OFF  400384      // ebuf: 800000 ushort (1.6 MB)
#define GCUR_OFF  2000384     // gcur: 196 int
#define GBASE_OFF 2001408     // gbase: 197 int
#define CCNT_OFF  2002432     // ccnt: 196 int
#define INV_OFF   3800576     // invdeg: 50000 f32
#define XBF_OFF   4000768     // x_bf:   50000x128 bf16 (12.8 MB)
#define AGG_OFF   16800768    // agg_bf: 50000x128 bf16
#define HBF_OFF   29600768    // h_bf: 50000x128 bf16; pairs (3.2 MB) borrows this early
#define PBF_OFF   42400768    // p_bf: 50000x64 bf16
#define WP1_OFF   48800768    // Wp1: 256x128 bf16 (64 KB)
#define WP2_OFF   48866304    // Wp2: 128x128 bf16 (32 KB)

// float -> bf16 bits (RNE), returned in high 16
__device__ __forceinline__ unsigned bfbits(float f) {
    unsigned u = __float_as_uint(f);
    return (u + 0x7fffu + ((u >> 16) & 1u)) & 0xffff0000u;
}
__device__ __forceinline__ unsigned short bf16r(float f) {
    return (unsigned short)(bfbits(f) >> 16);
}
__device__ __forceinline__ float blo(unsigned u) { return __uint_as_float(u << 16); }
__device__ __forceinline__ float bhi(unsigned u) { return __uint_as_float(u & 0xffff0000u); }

// ---- fused: x->bf16 conversion, ccnt zeroing, W packing ----
__global__ __launch_bounds__(256) void prep_kernel(const float4* __restrict__ x4,
                                                   uint2* __restrict__ xbf,
                                                   int* __restrict__ ccnt,
                                                   const float* __restrict__ Wl1,
                                                   const float* __restrict__ Wr1,
                                                   const float* __restrict__ Wl2,
                                                   const float* __restrict__ Wr2,
                                                   unsigned short* __restrict__ Wp1,
                                                   unsigned short* __restrict__ Wp2) {
    int bid = blockIdx.x;
    int t = threadIdx.x;
    if (bid < CONV_BLOCKS) {
        if (bid == 0 && t < NBUCKET) ccnt[t] = 0;
        int i = bid * 256 + t;
        float4 v = x4[i];
        uint2 o;
        o.x = (bfbits(v.x) >> 16) | bfbits(v.y);
        o.y = (bfbits(v.z) >> 16) | bfbits(v.w);
        xbf[i] = o;
    } else if (bid < CONV_BLOCKS + 128) {
        int idx = (bid - CONV_BLOCKS) * 256 + t;  // 256x128
        int k = idx >> 7, n = idx & 127;
        float v = (k < 128) ? Wl1[k * 128 + n] : Wr1[(k - 128) * 128 + n];
        Wp1[((k >> 5) << 12) + (n << 5) + (((k >> 3) & 3) << 3) + (k & 7)] = bf16r(v);
    } else {
        int idx = (bid - CONV_BLOCKS - 128) * 256 + t;  // 128x128
        int k = idx >> 7, n = idx & 127;
        float v = (n < 64) ? Wl2[k * 64 + n] : Wr2[k * 64 + (n - 64)];
        Wp2[((k >> 5) << 12) + (n << 5) + (((k >> 3) & 3) << 3) + (k & 7)] = bf16r(v);
    }
}

// ---- coarse histogram (196 bins), LDS-aggregated ----
__global__ __launch_bounds__(256) void histC_kernel(const int* __restrict__ dst,
                                                    int* __restrict__ ccnt, int E) {
    __shared__ int lh[256];
    int t = threadIdx.x;
    lh[t] = 0;
    __syncthreads();
    int e0 = blockIdx.x * CHUNK_A;
    int e1 = min(e0 + CHUNK_A, E);
    for (int e = e0 + t; e < e1; e += 256) atomicAdd(&lh[dst[e] >> 8], 1);
    __syncthreads();
    if (lh[t]) atomicAdd(&ccnt[t], lh[t]);
}

// ---- exclusive scan of 196 coarse counts -> gbase, gcur ----
__global__ __launch_bounds__(256) void scanG_kernel(const int* __restrict__ ccnt,
                                                    int* __restrict__ gbase,
                                                    int* __restrict__ gcur,
                                                    int* __restrict__ off, int E) {
    __shared__ int sm[256];
    int t = threadIdx.x;
    int v = (t < NBUCKET) ? ccnt[t] : 0;
    sm[t] = v;
    __syncthreads();
    for (int d = 1; d < 256; d <<= 1) {
        int u = (t >= d) ? sm[t - d] : 0;
        __syncthreads();
        sm[t] += u;
        __syncthreads();
    }
    int excl = sm[t] - v;
    if (t < NBUCKET) {
        gbase[t] = excl;
        gcur[t] = excl;
    }
    if (t == 0) {
        gbase[NBUCKET] = E;
        off[N_NODES] = E;
    }
}

// ---- pass A: coarse partition into 196 buckets, LDS-compacted dense writes ----
__global__ __launch_bounds__(256) void passA_kernel(const int* __restrict__ src,
                                                    const int* __restrict__ dst,
                                                    int* __restrict__ gcur,
                                                    unsigned* __restrict__ pairs, int E) {
    __shared__ int bh[256];    // hist -> exclusive base
    __shared__ int lcur[256];
    __shared__ int gb[256];
    __shared__ int sc[256];
    __shared__ unsigned lbuf[3328];
    int t = threadIdx.x;
    int e0 = blockIdx.x * CHUNK_A;
    int e1 = min(e0 + CHUNK_A, E);
    bh[t] = 0;
    lcur[t] = 0;
    __syncthreads();
    for (int e = e0 + t; e < e1; e += 256) atomicAdd(&bh[dst[e] >> 8], 1);
    __syncthreads();
    int v = bh[t];
    sc[t] = v;
    __syncthreads();
    for (int d = 1; d < 256; d <<= 1) {
        int u = (t >= d) ? sc[t - d] : 0;
        __syncthreads();
        sc[t] += u;
        __syncthreads();
    }
    int lbase = sc[t] - v;
    if (v > 0) gb[t] = atomicAdd(&gcur[t], v);  // claim contiguous run in bucket t
    bh[t] = lbase;
    __syncthreads();
    for (int e = e0 + t; e < e1; e += 256) {
        int s = src[e], d = dst[e];
        int b = d >> 8;
        int lpos = bh[b] + atomicAdd(&lcur[b], 1);
        lbuf[lpos] = (unsigned)s | ((unsigned)d << 16);
    }
    __syncthreads();
    int T = e1 - e0;
    for (int k = t; k < T; k += 256) {
        unsigned p = lbuf[k];
        int b = p >> 24;
        pairs[gb[b] + (k - bh[b])] = p;
    }
}

// ---- pass B: fine hist+scan in LDS -> off/invdeg, dense ushort ebuf write ----
__global__ __launch_bounds__(256) void passB_kernel(const int* __restrict__ gbase,
                                                    const unsigned* __restrict__ pairs,
                                                    int* __restrict__ off,
                                                    float* __restrict__ invdeg,
                                                    unsigned short* __restrict__ ebuf16) {
    __shared__ int fh[256];
    __shared__ int sc[256];
    __shared__ int lcnt[256];
    __shared__ unsigned short lout[PASSB_CAP];
    int b = blockIdx.x;
    int t = threadIdx.x;
    int gb = gbase[b];
    int W = gbase[b + 1] - gb;
    fh[t] = 0;
    __syncthreads();
    for (int k = t; k < W; k += 256) atomicAdd(&fh[(pairs[gb + k] >> 16) & 255], 1);
    __syncthreads();
    int c = fh[t];
    sc[t] = c;
    __syncthreads();
    for (int d = 1; d < 256; d <<= 1) {
        int u = (t >= d) ? sc[t - d] : 0;
        __syncthreads();
        sc[t] += u;
        __syncthreads();
    }
    int excl = sc[t] - c;
    int dg = b * 256 + t;
    if (dg < N_NODES) {
        off[dg] = gb + excl;
        invdeg[dg] = 1.0f / fmaxf((float)c, 1.0f);
    }
    lcnt[t] = excl;
    __syncthreads();
    if (W <= PASSB_CAP) {
        for (int k = t; k < W; k += 256) {
            unsigned p = pairs[gb + k];
            int dl = (p >> 16) & 255;
            int pos = atomicAdd(&lcnt[dl], 1);
            lout[pos] = (unsigned short)(p & 0xffffu);
        }
        __syncthreads();
        for (int k = t; k < W; k += 256) ebuf16[gb + k] = lout[k];
    } else {  // fallback: scattered writes within the bucket window (never for this input)
        for (int k = t; k < W; k += 256) {
            unsigned p = pairs[gb + k];
            int dl = (p >> 16) & 255;
            int pos = atomicAdd(&lcnt[dl], 1);
            ebuf16[gb + pos] = (unsigned short)(p & 0xffffu);
        }
    }
}

// ---- layer-1 gather: 4 groups x 16 lanes, 2 edges in flight per group ----
__global__ __launch_bounds__(64) void gather1_kernel(const int* __restrict__ off,
                                                     const unsigned short* __restrict__ ebuf,
                                                     const float* __restrict__ invdeg,
                                                     const uint4* __restrict__ xbf4,
                                                     uint4* __restrict__ aggbf4) {
    int d = blockIdx.x;
    int j = threadIdx.x;
    int g = j >> 4;
    int f = j & 15;
    int lo = off[d], hi = off[d + 1];
    float a[8] = {0.f, 0.f, 0.f, 0.f, 0.f, 0.f, 0.f, 0.f};
    int i = lo + g;
    for (; i + 4 < hi; i += 8) {
        int s0 = ebuf[i];
        int s1 = ebuf[i + 4];
        uint4 v0 = xbf4[(size_t)s0 * 16 + f];
        uint4 v1 = xbf4[(size_t)s1 * 16 + f];
        a[0] += blo(v0.x) + blo(v1.x); a[1] += bhi(v0.x) + bhi(v1.x);
        a[2] += blo(v0.y) + blo(v1.y); a[3] += bhi(v0.y) + bhi(v1.y);
        a[4] += blo(v0.z) + blo(v1.z); a[5] += bhi(v0.z) + bhi(v1.z);
        a[6] += blo(v0.w) + blo(v1.w); a[7] += bhi(v0.w) + bhi(v1.w);
    }
    if (i < hi) {
        uint4 v = xbf4[(size_t)ebuf[i] * 16 + f];
        a[0] += blo(v.x); a[1] += bhi(v.x);
        a[2] += blo(v.y); a[3] += bhi(v.y);
        a[4] += blo(v.z); a[5] += bhi(v.z);
        a[6] += blo(v.w); a[7] += bhi(v.w);
    }
#pragma unroll
    for (int q = 0; q < 8; ++q) {
        a[q] += __shfl_xor(a[q], 16, 64);
        a[q] += __shfl_xor(a[q], 32, 64);
    }
    if (g == 0) {
        float inv = invdeg[d];
        uint4 o;
        o.x = (bfbits(a[0] * inv) >> 16) | bfbits(a[1] * inv);
        o.y = (bfbits(a[2] * inv) >> 16) | bfbits(a[3] * inv);
        o.z = (bfbits(a[4] * inv) >> 16) | bfbits(a[5] * inv);
        o.w = (bfbits(a[6] * inv) >> 16) | bfbits(a[7] * inv);
        aggbf4[(size_t)d * 16 + f] = o;
    }
}

// ---- MFMA gemm1: h = relu([agg|x] @ Wp1 + b1) ; M=50000 K=256 N=128 ----
__global__ __launch_bounds__(256) void gemm1_kernel(const unsigned short* __restrict__ aggbf,
                                                    const unsigned short* __restrict__ xbf,
                                                    const unsigned short* __restrict__ Wp1,
                                                    const float* __restrict__ b1,
                                                    unsigned short* __restrict__ hbf) {
    int tile = blockIdx.x * 4 + (threadIdx.x >> 6);
    if (tile >= M_TILES) return;
    int lane = threadIdx.x & 63;
    int lo16 = lane & 15;
    int kg = lane >> 4;
    int m0 = tile * 16;

    f32x4 acc[8];
#pragma unroll
    for (int n = 0; n < 8; ++n) acc[n] = (f32x4){0.f, 0.f, 0.f, 0.f};

    int arow = m0 + lo16;
    const unsigned short* rowa = aggbf + (size_t)arow * 128;
    const unsigned short* rowx = xbf + (size_t)arow * 128;

#pragma unroll
    for (int ks = 0; ks < 8; ++ks) {
        const unsigned short* abase =
            (ks < 4 ? rowa + ks * 32 : rowx + (ks - 4) * 32) + kg * 8;
        bf16x8 a = *reinterpret_cast<const bf16x8*>(abase);
        const unsigned short* wbase = Wp1 + ks * 4096 + lo16 * 32 + kg * 8;
#pragma unroll
        for (int n = 0; n < 8; ++n) {
            bf16x8 b = *reinterpret_cast<const bf16x8*>(wbase + n * 512);
            acc[n] = __builtin_amdgcn_mfma_f32_16x16x32_bf16(a, b, acc[n], 0, 0, 0);
        }
    }

    int r0 = (lane >> 4) * 4;
#pragma unroll
    for (int n = 0; n < 8; ++n) {
        int col = n * 16 + lo16;
        float bv = b1[col];
#pragma unroll
        for (int r = 0; r < 4; ++r) {
            int row = m0 + r0 + r;
            float v = acc[n][r] + bv;
            hbf[(size_t)row * 128 + col] = bf16r(fmaxf(v, 0.0f));
        }
    }
}

// ---- MFMA gemm2: [p | out] = h @ Wp2 (+b2 on right half) ; M=50000 K=128 N=128 ----
__global__ __launch_bounds__(256) void gemm2_kernel(const unsigned short* __restrict__ hbf,
                                                    const unsigned short* __restrict__ Wp2,
                                                    const float* __restrict__ b2,
                                                    unsigned short* __restrict__ pbf,
                                                    float* __restrict__ out) {
    int tile = blockIdx.x * 4 + (threadIdx.x >> 6);
    if (tile >= M_TILES) return;
    int lane = threadIdx.x & 63;
    int lo16 = lane & 15;
    int kg = lane >> 4;
    int m0 = tile * 16;

    f32x4 acc[8];
#pragma unroll
    for (int n = 0; n < 8; ++n) acc[n] = (f32x4){0.f, 0.f, 0.f, 0.f};

    const unsigned short* rowh = hbf + (size_t)(m0 + lo16) * 128;

#pragma unroll
    for (int ks = 0; ks < 4; ++ks) {
        bf16x8 a = *reinterpret_cast<const bf16x8*>(rowh + ks * 32 + kg * 8);
        const unsigned short* wbase = Wp2 + ks * 4096 + lo16 * 32 + kg * 8;
#pragma unroll
        for (int n = 0; n < 8; ++n) {
            bf16x8 b = *reinterpret_cast<const bf16x8*>(wbase + n * 512);
            acc[n] = __builtin_amdgcn_mfma_f32_16x16x32_bf16(a, b, acc[n], 0, 0, 0);
        }
    }

    int r0 = (lane >> 4) * 4;
#pragma unroll
    for (int n = 0; n < 8; ++n) {
        int col = n * 16 + lo16;
        if (col < 64) {
#pragma unroll
            for (int r = 0; r < 4; ++r) {
                int row = m0 + r0 + r;
                pbf[(size_t)row * 64 + col] = bf16r(acc[n][r]);
            }
        } else {
            float bv = b2[col - 64];
#pragma unroll
            for (int r = 0; r < 4; ++r) {
                int row = m0 + r0 + r;
                out[(size_t)row * 64 + (col - 64)] = acc[n][r] + bv;
            }
        }
    }
}

// ---- layer-2 gather: 4 groups x 16 lanes, 2 edges in flight per group ----
__global__ __launch_bounds__(64) void gather2_kernel(const int* __restrict__ off,
                                                     const unsigned short* __restrict__ ebuf,
                                                     const float* __restrict__ invdeg,
                                                     const uint2* __restrict__ pbf2,
                                                     float4* __restrict__ out4) {
    int d = blockIdx.x;
    int j = threadIdx.x;
    int g = j >> 4;
    int f = j & 15;
    int lo = off[d], hi = off[d + 1];
    float a0 = 0.f, a1 = 0.f, a2 = 0.f, a3 = 0.f;
    int i = lo + g;
    for (; i + 4 < hi; i += 8) {
        int s0 = ebuf[i];
        int s1 = ebuf[i + 4];
        uint2 v0 = pbf2[(size_t)s0 * 16 + f];
        uint2 v1 = pbf2[(size_t)s1 * 16 + f];
        a0 += blo(v0.x) + blo(v1.x); a1 += bhi(v0.x) + bhi(v1.x);
        a2 += blo(v0.y) + blo(v1.y); a3 += bhi(v0.y) + bhi(v1.y);
    }
    if (i < hi) {
        uint2 v = pbf2[(size_t)ebuf[i] * 16 + f];
        a0 += blo(v.x); a1 += bhi(v.x);
        a2 += blo(v.y); a3 += bhi(v.y);
    }
    a0 += __shfl_xor(a0, 16, 64); a0 += __shfl_xor(a0, 32, 64);
    a1 += __shfl_xor(a1, 16, 64); a1 += __shfl_xor(a1, 32, 64);
    a2 += __shfl_xor(a2, 16, 64); a2 += __shfl_xor(a2, 32, 64);
    a3 += __shfl_xor(a3, 16, 64); a3 += __shfl_xor(a3, 32, 64);
    if (g == 0) {
        float inv = invdeg[d];
        float4* op = out4 + (size_t)d * 16 + f;
        float4 o = *op;
        o.x += a0 * inv;
        o.y += a1 * inv;
        o.z += a2 * inv;
        o.w += a3 * inv;
        *op = o;
    }
}

extern "C" void kernel_launch(void* const* d_in, const int* in_sizes, int n_in,
                              void* d_out, int out_size, void* d_ws, size_t ws_size,
                              hipStream_t stream) {
    const float* x   = (const float*)d_in[0];
    const int*   ei  = (const int*)d_in[1];
    const float* Wl1 = (const float*)d_in[2];
    const float* b1  = (const float*)d_in[3];
    const float* Wr1 = (const float*)d_in[4];
    const float* Wl2 = (const float*)d_in[5];
    const float* b2  = (const float*)d_in[6];
    const float* Wr2 = (const float*)d_in[7];
    float* out = (float*)d_out;

    const int E = in_sizes[1] / 2;
    const int* src = ei;
    const int* dst = ei + E;

    char* ws = (char*)d_ws;
    int*            off    = (int*)(ws + OFF_OFF);
    unsigned short* ebuf16 = (unsigned short*)(ws + EBUF_OFF);
    int*            gcur   = (int*)(ws + GCUR_OFF);
    int*            gbase  = (int*)(ws + GBASE_OFF);
    int*            ccnt   = (int*)(ws + CCNT_OFF);
    float*          invdeg = (float*)(ws + INV_OFF);
    unsigned*       xbf    = (unsigned*)(ws + XBF_OFF);
    unsigned*       aggbf  = (unsigned*)(ws + AGG_OFF);
    unsigned short* hbf    = (unsigned short*)(ws + HBF_OFF);
    unsigned*       pairs  = (unsigned*)(ws + HBF_OFF);   // borrowed before gemm1 writes hbf
    unsigned short* pbf    = (unsigned short*)(ws + PBF_OFF);
    unsigned short* Wp1    = (unsigned short*)(ws + WP1_OFF);
    unsigned short* Wp2    = (unsigned short*)(ws + WP2_OFF);

    // fused conversion + weight packing (+ ccnt zeroing)
    prep_kernel<<<CONV_BLOCKS + 192, 256, 0, stream>>>((const float4*)x, (uint2*)xbf, ccnt,
                                                       Wl1, Wr1, Wl2, Wr2, Wp1, Wp2);

    // dst-CSR build: coarse hist -> coarse scan -> partition -> fine order (+off/invdeg)
    histC_kernel<<<(E + CHUNK_A - 1) / CHUNK_A, 256, 0, stream>>>(dst, ccnt, E);
    scanG_kernel<<<1, 256, 0, stream>>>(ccnt, gbase, gcur, off, E);
    passA_kernel<<<(E + CHUNK_A - 1) / CHUNK_A, 256, 0, stream>>>(src, dst, gcur, pairs, E);
    passB_kernel<<<NBUCKET, 256, 0, stream>>>(gbase, pairs, off, invdeg, ebuf16);

    // layer 1
    gather1_kernel<<<N_NODES, 64, 0, stream>>>(off, ebuf16, invdeg, (const uint4*)xbf,
                                               (uint4*)aggbf);
    gemm1_kernel<<<(M_TILES + 3) / 4, 256, 0, stream>>>((const unsigned short*)aggbf,
                                                        (const unsigned short*)xbf, Wp1, b1, hbf);

    // layer 2 (project-then-aggregate)
    gemm2_kernel<<<(M_TILES + 3) / 4, 256, 0, stream>>>(hbf, Wp2, b2, pbf, out);
    gather2_kernel<<<N_NODES, 64, 0, stream>>>(off, ebuf16, invdeg, (const uint2*)pbf,
                                               (float4*)out);
}

// Round 9
// 126.703 us; speedup vs baseline: 17.6814x; 1.0451x over previous
//
#include <hip/hip_runtime.h>
#include <hip/hip_bf16.h>

#define N_NODES 50000
#define M_TILES 3125   // 50000/16
#define NBUCKET 196    // coarse buckets (dst>>8)
#define CHUNK_A 3125   // edges per passA/histC block
#define PASSB_CAP 12288
#define CONV_BLOCKS 6250   // N_NODES*32/256

typedef __attribute__((ext_vector_type(8))) __bf16 bf16x8;
typedef __attribute__((ext_vector_type(4))) float f32x4;

// ---------------- workspace layout (bytes) ----------------
#define OFF_OFF   0            // off:  50001 int
#define EBUF_OFF  400384      // ebuf: 800000 ushort (1.6 MB)
#define GCUR_OFF  2000384     // gcur: 196 int
#define CCNT_OFF  2002432     // ccnt: 196 int
#define INV_OFF   3800576     // invdeg: 50000 f32
#define XBF_OFF   4000768     // x_bf:   50000x128 bf16 (12.8 MB)
#define AGG_OFF   16800768    // agg_bf: 50000x128 bf16
#define PAIRS_OFF 29600768    // pairs: 800000 uint (3.2 MB)
#define PBF_OFF   42400768    // p_bf: 50000x64 bf16
#define WP1_OFF   48800768    // Wp1: 256x128 bf16 (64 KB)
#define WP2_OFF   48866304    // Wp2: 128x128 bf16 (32 KB)

// float -> bf16 bits (RNE), returned in high 16
__device__ __forceinline__ unsigned bfbits(float f) {
    unsigned u = __float_as_uint(f);
    return (u + 0x7fffu + ((u >> 16) & 1u)) & 0xffff0000u;
}
__device__ __forceinline__ unsigned short bf16r(float f) {
    return (unsigned short)(bfbits(f) >> 16);
}
__device__ __forceinline__ float blo(unsigned u) { return __uint_as_float(u << 16); }
__device__ __forceinline__ float bhi(unsigned u) { return __uint_as_float(u & 0xffff0000u); }

// ---- fused: x->bf16 conversion, ccnt zeroing, W packing ----
__global__ __launch_bounds__(256) void prep_kernel(const float4* __restrict__ x4,
                                                   uint2* __restrict__ xbf,
                                                   int* __restrict__ ccnt,
                                                   const float* __restrict__ Wl1,
                                                   const float* __restrict__ Wr1,
                                                   const float* __restrict__ Wl2,
                                                   const float* __restrict__ Wr2,
                                                   unsigned short* __restrict__ Wp1,
                                                   unsigned short* __restrict__ Wp2) {
    int bid = blockIdx.x;
    int t = threadIdx.x;
    if (bid < CONV_BLOCKS) {
        if (bid == 0 && t < NBUCKET) ccnt[t] = 0;
        int i = bid * 256 + t;
        float4 v = x4[i];
        uint2 o;
        o.x = (bfbits(v.x) >> 16) | bfbits(v.y);
        o.y = (bfbits(v.z) >> 16) | bfbits(v.w);
        xbf[i] = o;
    } else if (bid < CONV_BLOCKS + 128) {
        int idx = (bid - CONV_BLOCKS) * 256 + t;  // 256x128
        int k = idx >> 7, n = idx & 127;
        float v = (k < 128) ? Wl1[k * 128 + n] : Wr1[(k - 128) * 128 + n];
        Wp1[((k >> 5) << 12) + (n << 5) + (((k >> 3) & 3) << 3) + (k & 7)] = bf16r(v);
    } else {
        int idx = (bid - CONV_BLOCKS - 128) * 256 + t;  // 128x128
        int k = idx >> 7, n = idx & 127;
        float v = (n < 64) ? Wl2[k * 64 + n] : Wr2[k * 64 + (n - 64)];
        Wp2[((k >> 5) << 12) + (n << 5) + (((k >> 3) & 3) << 3) + (k & 7)] = bf16r(v);
    }
}

// ---- coarse histogram (196 bins), LDS-aggregated; block 0 zeroes gcur ----
__global__ __launch_bounds__(256) void histC_kernel(const int* __restrict__ dst,
                                                    int* __restrict__ ccnt,
                                                    int* __restrict__ gcur, int E) {
    __shared__ int lh[256];
    int t = threadIdx.x;
    if (blockIdx.x == 0 && t < NBUCKET) gcur[t] = 0;
    lh[t] = 0;
    __syncthreads();
    int e0 = blockIdx.x * CHUNK_A;
    int e1 = min(e0 + CHUNK_A, E);
    for (int e = e0 + t; e < e1; e += 256) atomicAdd(&lh[dst[e] >> 8], 1);
    __syncthreads();
    if (lh[t]) atomicAdd(&ccnt[t], lh[t]);
}

// ---- pass A: coarse partition into 196 buckets, LDS-compacted dense writes ----
__global__ __launch_bounds__(256) void passA_kernel(const int* __restrict__ src,
                                                    const int* __restrict__ dst,
                                                    const int* __restrict__ ccnt,
                                                    int* __restrict__ gcur,
                                                    unsigned* __restrict__ pairs, int E) {
    __shared__ int bh[256];    // hist -> exclusive base
    __shared__ int lcur[256];
    __shared__ int gb[256];
    __shared__ int sc[256];
    __shared__ unsigned lbuf[3328];
    int t = threadIdx.x;
    // local scan of coarse counts -> per-thread gbase
    int cc = (t < NBUCKET) ? ccnt[t] : 0;
    sc[t] = cc;
    __syncthreads();
    for (int d = 1; d < 256; d <<= 1) {
        int u = (t >= d) ? sc[t - d] : 0;
        __syncthreads();
        sc[t] += u;
        __syncthreads();
    }
    int gbase_t = sc[t] - cc;
    int e0 = blockIdx.x * CHUNK_A;
    int e1 = min(e0 + CHUNK_A, E);
    bh[t] = 0;
    lcur[t] = 0;
    __syncthreads();
    for (int e = e0 + t; e < e1; e += 256) atomicAdd(&bh[dst[e] >> 8], 1);
    __syncthreads();
    int v = bh[t];
    sc[t] = v;
    __syncthreads();
    for (int d = 1; d < 256; d <<= 1) {
        int u = (t >= d) ? sc[t - d] : 0;
        __syncthreads();
        sc[t] += u;
        __syncthreads();
    }
    int lbase = sc[t] - v;
    if (v > 0) gb[t] = gbase_t + atomicAdd(&gcur[t], v);  // claim contiguous run
    bh[t] = lbase;
    __syncthreads();
    for (int e = e0 + t; e < e1; e += 256) {
        int s = src[e], d = dst[e];
        int b = d >> 8;
        int lpos = bh[b] + atomicAdd(&lcur[b], 1);
        lbuf[lpos] = (unsigned)s | ((unsigned)d << 16);
    }
    __syncthreads();
    int T = e1 - e0;
    for (int k = t; k < T; k += 256) {
        unsigned p = lbuf[k];
        int b = p >> 24;
        pairs[gb[b] + (k - bh[b])] = p;
    }
}

// ---- pass B: fine hist+scan in LDS -> off/invdeg, dense ushort ebuf write ----
__global__ __launch_bounds__(256) void passB_kernel(const int* __restrict__ ccnt,
                                                    const unsigned* __restrict__ pairs,
                                                    int* __restrict__ off,
                                                    float* __restrict__ invdeg,
                                                    unsigned short* __restrict__ ebuf16,
                                                    int E) {
    __shared__ int sc[256];
    __shared__ int fh[256];
    __shared__ int lcnt[256];
    __shared__ int sGb, sW;
    __shared__ unsigned short lout[PASSB_CAP];
    int b = blockIdx.x;
    int t = threadIdx.x;
    // local scan of coarse counts -> this bucket's base & width
    int cc = (t < NBUCKET) ? ccnt[t] : 0;
    sc[t] = cc;
    __syncthreads();
    for (int d = 1; d < 256; d <<= 1) {
        int u = (t >= d) ? sc[t - d] : 0;
        __syncthreads();
        sc[t] += u;
        __syncthreads();
    }
    if (t == b) { sGb = sc[t] - cc; sW = cc; }
    fh[t] = 0;
    __syncthreads();
    int gb = sGb, W = sW;
    for (int k = t; k < W; k += 256) atomicAdd(&fh[(pairs[gb + k] >> 16) & 255], 1);
    __syncthreads();
    int c = fh[t];
    sc[t] = c;
    __syncthreads();
    for (int d = 1; d < 256; d <<= 1) {
        int u = (t >= d) ? sc[t - d] : 0;
        __syncthreads();
        sc[t] += u;
        __syncthreads();
    }
    int excl = sc[t] - c;
    int dg = b * 256 + t;
    if (dg < N_NODES) {
        off[dg] = gb + excl;
        invdeg[dg] = 1.0f / fmaxf((float)c, 1.0f);
    }
    if (b == NBUCKET - 1 && t == 0) off[N_NODES] = E;
    lcnt[t] = excl;
    __syncthreads();
    if (W <= PASSB_CAP) {
        for (int k = t; k < W; k += 256) {
            unsigned p = pairs[gb + k];
            int dl = (p >> 16) & 255;
            int pos = atomicAdd(&lcnt[dl], 1);
            lout[pos] = (unsigned short)(p & 0xffffu);
        }
        __syncthreads();
        for (int k = t; k < W; k += 256) ebuf16[gb + k] = lout[k];
    } else {  // fallback (never for this input)
        for (int k = t; k < W; k += 256) {
            unsigned p = pairs[gb + k];
            int dl = (p >> 16) & 255;
            int pos = atomicAdd(&lcnt[dl], 1);
            ebuf16[gb + pos] = (unsigned short)(p & 0xffffu);
        }
    }
}

// ---- layer-1 gather: 4 groups x 16 lanes, 4 edges in flight per group ----
__global__ __launch_bounds__(64) void gather1_kernel(const int* __restrict__ off,
                                                     const unsigned short* __restrict__ ebuf,
                                                     const float* __restrict__ invdeg,
                                                     const uint4* __restrict__ xbf4,
                                                     uint4* __restrict__ aggbf4) {
    int d = blockIdx.x;
    int j = threadIdx.x;
    int g = j >> 4;
    int f = j & 15;
    int lo = off[d], hi = off[d + 1];
    float a[8] = {0.f, 0.f, 0.f, 0.f, 0.f, 0.f, 0.f, 0.f};
    int i = lo + g;
    for (; i + 12 < hi; i += 16) {
        int s0 = ebuf[i], s1 = ebuf[i + 4], s2 = ebuf[i + 8], s3 = ebuf[i + 12];
        uint4 v0 = xbf4[(size_t)s0 * 16 + f];
        uint4 v1 = xbf4[(size_t)s1 * 16 + f];
        uint4 v2 = xbf4[(size_t)s2 * 16 + f];
        uint4 v3 = xbf4[(size_t)s3 * 16 + f];
        a[0] += blo(v0.x) + blo(v1.x) + blo(v2.x) + blo(v3.x);
        a[1] += bhi(v0.x) + bhi(v1.x) + bhi(v2.x) + bhi(v3.x);
        a[2] += blo(v0.y) + blo(v1.y) + blo(v2.y) + blo(v3.y);
        a[3] += bhi(v0.y) + bhi(v1.y) + bhi(v2.y) + bhi(v3.y);
        a[4] += blo(v0.z) + blo(v1.z) + blo(v2.z) + blo(v3.z);
        a[5] += bhi(v0.z) + bhi(v1.z) + bhi(v2.z) + bhi(v3.z);
        a[6] += blo(v0.w) + blo(v1.w) + blo(v2.w) + blo(v3.w);
        a[7] += bhi(v0.w) + bhi(v1.w) + bhi(v2.w) + bhi(v3.w);
    }
    for (; i < hi; i += 4) {
        uint4 v = xbf4[(size_t)ebuf[i] * 16 + f];
        a[0] += blo(v.x); a[1] += bhi(v.x);
        a[2] += blo(v.y); a[3] += bhi(v.y);
        a[4] += blo(v.z); a[5] += bhi(v.z);
        a[6] += blo(v.w); a[7] += bhi(v.w);
    }
#pragma unroll
    for (int q = 0; q < 8; ++q) {
        a[q] += __shfl_xor(a[q], 16, 64);
        a[q] += __shfl_xor(a[q], 32, 64);
    }
    if (g == 0) {
        float inv = invdeg[d];
        uint4 o;
        o.x = (bfbits(a[0] * inv) >> 16) | bfbits(a[1] * inv);
        o.y = (bfbits(a[2] * inv) >> 16) | bfbits(a[3] * inv);
        o.z = (bfbits(a[4] * inv) >> 16) | bfbits(a[5] * inv);
        o.w = (bfbits(a[6] * inv) >> 16) | bfbits(a[7] * inv);
        aggbf4[(size_t)d * 16 + f] = o;
    }
}

// ---- fused MFMA gemm: h = relu([agg|x]@Wp1+b1) (kept in LDS), then
//      [p | out] = h @ Wp2 (+b2 on right half).  M=50000, per-wave 16-row tile ----
__global__ __launch_bounds__(256) void gemmF_kernel(const unsigned short* __restrict__ aggbf,
                                                    const unsigned short* __restrict__ xbf,
                                                    const unsigned short* __restrict__ Wp1,
                                                    const float* __restrict__ b1,
                                                    const unsigned short* __restrict__ Wp2,
                                                    const float* __restrict__ b2,
                                                    unsigned short* __restrict__ pbf,
                                                    float* __restrict__ out) {
    __shared__ unsigned short hsm[4][2048];  // per-wave 16x128 bf16 tile (swizzled)
    int w = threadIdx.x >> 6;
    int tile = blockIdx.x * 4 + w;
    bool active = tile < M_TILES;
    if (!active) tile = M_TILES - 1;   // keep wave alive for the barrier
    int lane = threadIdx.x & 63;
    int lo16 = lane & 15;
    int kg = lane >> 4;
    int m0 = tile * 16;
    int r0 = kg * 4;

    // ---- phase 1: [agg|x] @ Wp1 ----
    f32x4 acc[8];
#pragma unroll
    for (int n = 0; n < 8; ++n) acc[n] = (f32x4){0.f, 0.f, 0.f, 0.f};
    const unsigned short* rowa = aggbf + (size_t)(m0 + lo16) * 128;
    const unsigned short* rowx = xbf + (size_t)(m0 + lo16) * 128;
#pragma unroll
    for (int ks = 0; ks < 8; ++ks) {
        const unsigned short* abase =
            (ks < 4 ? rowa + ks * 32 : rowx + (ks - 4) * 32) + kg * 8;
        bf16x8 a = *reinterpret_cast<const bf16x8*>(abase);
        const unsigned short* wbase = Wp1 + ks * 4096 + lo16 * 32 + kg * 8;
#pragma unroll
        for (int n = 0; n < 8; ++n) {
            bf16x8 b = *reinterpret_cast<const bf16x8*>(wbase + n * 512);
            acc[n] = __builtin_amdgcn_mfma_f32_16x16x32_bf16(a, b, acc[n], 0, 0, 0);
        }
    }

    // ---- h tile -> LDS (bias+relu+bf16), XOR-swizzled rows ----
    unsigned short* hs = hsm[w];
#pragma unroll
    for (int n = 0; n < 8; ++n) {
        int col = n * 16 + lo16;
        float bv = b1[col];
#pragma unroll
        for (int r = 0; r < 4; ++r) {
            int row = r0 + r;
            float v = fmaxf(acc[n][r] + bv, 0.0f);
            hs[row * 128 + (col ^ ((row & 7) << 3))] = bf16r(v);
        }
    }
    __syncthreads();

    // ---- phase 2: h @ Wp2 from LDS ----
    f32x4 acc2[8];
#pragma unroll
    for (int n = 0; n < 8; ++n) acc2[n] = (f32x4){0.f, 0.f, 0.f, 0.f};
#pragma unroll
    for (int ks = 0; ks < 4; ++ks) {
        int base0 = (ks * 32 + kg * 8) ^ ((lo16 & 7) << 3);
        bf16x8 a2 = *reinterpret_cast<const bf16x8*>(&hs[lo16 * 128 + base0]);
        const unsigned short* wbase = Wp2 + ks * 4096 + lo16 * 32 + kg * 8;
#pragma unroll
        for (int n = 0; n < 8; ++n) {
            bf16x8 b = *reinterpret_cast<const bf16x8*>(wbase + n * 512);
            acc2[n] = __builtin_amdgcn_mfma_f32_16x16x32_bf16(a2, b, acc2[n], 0, 0, 0);
        }
    }

    if (!active) return;
#pragma unroll
    for (int n = 0; n < 8; ++n) {
        int col = n * 16 + lo16;
        if (col < 64) {
#pragma unroll
            for (int r = 0; r < 4; ++r) {
                int row = m0 + r0 + r;
                pbf[(size_t)row * 64 + col] = bf16r(acc2[n][r]);
            }
        } else {
            float bv = b2[col - 64];
#pragma unroll
            for (int r = 0; r < 4; ++r) {
                int row = m0 + r0 + r;
                out[(size_t)row * 64 + (col - 64)] = acc2[n][r] + bv;
            }
        }
    }
}

// ---- layer-2 gather: 4 groups x 16 lanes, 4 edges in flight per group ----
__global__ __launch_bounds__(64) void gather2_kernel(const int* __restrict__ off,
                                                     const unsigned short* __restrict__ ebuf,
                                                     const float* __restrict__ invdeg,
                                                     const uint2* __restrict__ pbf2,
                                                     float4* __restrict__ out4) {
    int d = blockIdx.x;
    int j = threadIdx.x;
    int g = j >> 4;
    int f = j & 15;
    int lo = off[d], hi = off[d + 1];
    float a0 = 0.f, a1 = 0.f, a2 = 0.f, a3 = 0.f;
    int i = lo + g;
    for (; i + 12 < hi; i += 16) {
        int s0 = ebuf[i], s1 = ebuf[i + 4], s2 = ebuf[i + 8], s3 = ebuf[i + 12];
        uint2 v0 = pbf2[(size_t)s0 * 16 + f];
        uint2 v1 = pbf2[(size_t)s1 * 16 + f];
        uint2 v2 = pbf2[(size_t)s2 * 16 + f];
        uint2 v3 = pbf2[(size_t)s3 * 16 + f];
        a0 += blo(v0.x) + blo(v1.x) + blo(v2.x) + blo(v3.x);
        a1 += bhi(v0.x) + bhi(v1.x) + bhi(v2.x) + bhi(v3.x);
        a2 += blo(v0.y) + blo(v1.y) + blo(v2.y) + blo(v3.y);
        a3 += bhi(v0.y) + bhi(v1.y) + bhi(v2.y) + bhi(v3.y);
    }
    for (; i < hi; i += 4) {
        uint2 v = pbf2[(size_t)ebuf[i] * 16 + f];
        a0 += blo(v.x); a1 += bhi(v.x);
        a2 += blo(v.y); a3 += bhi(v.y);
    }
    a0 += __shfl_xor(a0, 16, 64); a0 += __shfl_xor(a0, 32, 64);
    a1 += __shfl_xor(a1, 16, 64); a1 += __shfl_xor(a1, 32, 64);
    a2 += __shfl_xor(a2, 16, 64); a2 += __shfl_xor(a2, 32, 64);
    a3 += __shfl_xor(a3, 16, 64); a3 += __shfl_xor(a3, 32, 64);
    if (g == 0) {
        float inv = invdeg[d];
        float4* op = out4 + (size_t)d * 16 + f;
        float4 o = *op;
        o.x += a0 * inv;
        o.y += a1 * inv;
        o.z += a2 * inv;
        o.w += a3 * inv;
        *op = o;
    }
}

extern "C" void kernel_launch(void* const* d_in, const int* in_sizes, int n_in,
                              void* d_out, int out_size, void* d_ws, size_t ws_size,
                              hipStream_t stream) {
    const float* x   = (const float*)d_in[0];
    const int*   ei  = (const int*)d_in[1];
    const float* Wl1 = (const float*)d_in[2];
    const float* b1  = (const float*)d_in[3];
    const float* Wr1 = (const float*)d_in[4];
    const float* Wl2 = (const float*)d_in[5];
    const float* b2  = (const float*)d_in[6];
    const float* Wr2 = (const float*)d_in[7];
    float* out = (float*)d_out;

    const int E = in_sizes[1] / 2;
    const int* src = ei;
    const int* dst = ei + E;

    char* ws = (char*)d_ws;
    int*            off    = (int*)(ws + OFF_OFF);
    unsigned short* ebuf16 = (unsigned short*)(ws + EBUF_OFF);
    int*            gcur   = (int*)(ws + GCUR_OFF);
    int*            ccnt   = (int*)(ws + CCNT_OFF);
    float*          invdeg = (float*)(ws + INV_OFF);
    unsigned*       xbf    = (unsigned*)(ws + XBF_OFF);
    unsigned*       aggbf  = (unsigned*)(ws + AGG_OFF);
    unsigned*       pairs  = (unsigned*)(ws + PAIRS_OFF);
    unsigned short* pbf    = (unsigned short*)(ws + PBF_OFF);
    unsigned short* Wp1    = (unsigned short*)(ws + WP1_OFF);
    unsigned short* Wp2    = (unsigned short*)(ws + WP2_OFF);

    // fused conversion + weight packing + ccnt zeroing
    prep_kernel<<<CONV_BLOCKS + 192, 256, 0, stream>>>((const float4*)x, (uint2*)xbf, ccnt,
                                                       Wl1, Wr1, Wl2, Wr2, Wp1, Wp2);

    // dst-CSR build: coarse hist (+gcur zero) -> partition -> fine order (+off/invdeg)
    histC_kernel<<<(E + CHUNK_A - 1) / CHUNK_A, 256, 0, stream>>>(dst, ccnt, gcur, E);
    passA_kernel<<<(E + CHUNK_A - 1) / CHUNK_A, 256, 0, stream>>>(src, dst, ccnt, gcur,
                                                                  pairs, E);
    passB_kernel<<<NBUCKET, 256, 0, stream>>>(ccnt, pairs, off, invdeg, ebuf16, E);

    // layer 1 aggregate
    gather1_kernel<<<N_NODES, 64, 0, stream>>>(off, ebuf16, invdeg, (const uint4*)xbf,
                                               (uint4*)aggbf);

    // fused layer-1 + layer-2 dense (h stays in LDS)
    gemmF_kernel<<<(M_TILES + 3) / 4, 256, 0, stream>>>((const unsigned short*)aggbf,
                                                        (const unsigned short*)xbf,
                                                        Wp1, b1, Wp2, b2, pbf, out);

    // layer 2 aggregate (project-then-aggregate)
    gather2_kernel<<<N_NODES, 64, 0, stream>>>(off, ebuf16, invdeg, (const uint2*)pbf,
                                               (float4*)out);
}

// Round 10
// 112.364 us; speedup vs baseline: 19.9377x; 1.1276x over previous
//
#include <hip/hip_runtime.h>
#include <hip/hip_bf16.h>

#define N_NODES 50000
#define M_TILES 3125   // 50000/16
#define NBUCKET 196    // coarse buckets (dst>>8)
#define CAP 5120       // fixed bucket capacity (mean 4096 + 16 sigma)
#define CHUNK_A 3125   // edges per passA block
#define CONV_BLOCKS 6250   // N_NODES*32/256

typedef __attribute__((ext_vector_type(8))) __bf16 bf16x8;
typedef __attribute__((ext_vector_type(4))) float f32x4;

// ---------------- workspace layout (bytes) ----------------
#define OFF_OFF   0           // off:  50000 int (row starts)
#define OFFE_OFF  200192     // offE: 50000 int (row ends)
#define EBUF_OFF  400384     // ebuf: 196*5120 ushort (2.0 MB)
#define GCUR_OFF  2407424    // gcur: 196 int
#define INV_OFF   3800576    // invdeg: 50000 f32
#define XBF_OFF   4000768    // x_bf:   50000x128 bf16 (12.8 MB)
#define AGG_OFF   16800768   // agg_bf: 50000x128 bf16
#define PAIRS_OFF 29600768   // pairs: 196*5120 uint (4.0 MB)
#define PBF_OFF   42400768   // p_bf: 50000x64 bf16
#define WP1_OFF   48800768   // Wp1: 256x128 bf16 (64 KB)
#define WP2_OFF   48866304   // Wp2: 128x128 bf16 (32 KB)

// float -> bf16 bits (RNE), returned in high 16
__device__ __forceinline__ unsigned bfbits(float f) {
    unsigned u = __float_as_uint(f);
    return (u + 0x7fffu + ((u >> 16) & 1u)) & 0xffff0000u;
}
__device__ __forceinline__ unsigned short bf16r(float f) {
    return (unsigned short)(bfbits(f) >> 16);
}
__device__ __forceinline__ float blo(unsigned u) { return __uint_as_float(u << 16); }
__device__ __forceinline__ float bhi(unsigned u) { return __uint_as_float(u & 0xffff0000u); }

// ---- fused: x->bf16 conversion, gcur zeroing, W packing ----
__global__ __launch_bounds__(256) void prep_kernel(const float4* __restrict__ x4,
                                                   uint2* __restrict__ xbf,
                                                   int* __restrict__ gcur,
                                                   const float* __restrict__ Wl1,
                                                   const float* __restrict__ Wr1,
                                                   const float* __restrict__ Wl2,
                                                   const float* __restrict__ Wr2,
                                                   unsigned short* __restrict__ Wp1,
                                                   unsigned short* __restrict__ Wp2) {
    int bid = blockIdx.x;
    int t = threadIdx.x;
    if (bid < CONV_BLOCKS) {
        if (bid == 0 && t < NBUCKET) gcur[t] = 0;
        int i = bid * 256 + t;
        float4 v = x4[i];
        uint2 o;
        o.x = (bfbits(v.x) >> 16) | bfbits(v.y);
        o.y = (bfbits(v.z) >> 16) | bfbits(v.w);
        xbf[i] = o;
    } else if (bid < CONV_BLOCKS + 128) {
        int idx = (bid - CONV_BLOCKS) * 256 + t;  // 256x128
        int k = idx >> 7, n = idx & 127;
        float v = (k < 128) ? Wl1[k * 128 + n] : Wr1[(k - 128) * 128 + n];
        Wp1[((k >> 5) << 12) + (n << 5) + (((k >> 3) & 3) << 3) + (k & 7)] = bf16r(v);
    } else {
        int idx = (bid - CONV_BLOCKS - 128) * 256 + t;  // 128x128
        int k = idx >> 7, n = idx & 127;
        float v = (n < 64) ? Wl2[k * 64 + n] : Wr2[k * 64 + (n - 64)];
        Wp2[((k >> 5) << 12) + (n << 5) + (((k >> 3) & 3) << 3) + (k & 7)] = bf16r(v);
    }
}

// ---- pass A: coarse partition into fixed-capacity buckets, LDS-compacted ----
__global__ __launch_bounds__(256) void passA_kernel(const int* __restrict__ src,
                                                    const int* __restrict__ dst,
                                                    int* __restrict__ gcur,
                                                    unsigned* __restrict__ pairs, int E) {
    __shared__ int bh[256];    // hist -> exclusive base
    __shared__ int lcur[256];
    __shared__ int gb[256];
    __shared__ int sc[256];
    __shared__ unsigned lbuf[3328];
    int t = threadIdx.x;
    int e0 = blockIdx.x * CHUNK_A;
    int e1 = min(e0 + CHUNK_A, E);
    bh[t] = 0;
    lcur[t] = 0;
    __syncthreads();
    for (int e = e0 + t; e < e1; e += 256) atomicAdd(&bh[dst[e] >> 8], 1);
    __syncthreads();
    int v = bh[t];
    sc[t] = v;
    __syncthreads();
    for (int d = 1; d < 256; d <<= 1) {
        int u = (t >= d) ? sc[t - d] : 0;
        __syncthreads();
        sc[t] += u;
        __syncthreads();
    }
    int lbase = sc[t] - v;
    if (v > 0) gb[t] = t * CAP + atomicAdd(&gcur[t], v);  // claim run in bucket t
    bh[t] = lbase;
    __syncthreads();
    for (int e = e0 + t; e < e1; e += 256) {
        int s = src[e], d = dst[e];
        int b = d >> 8;
        int lpos = bh[b] + atomicAdd(&lcur[b], 1);
        lbuf[lpos] = (unsigned)s | ((unsigned)d << 16);
    }
    __syncthreads();
    int T = e1 - e0;
    for (int k = t; k < T; k += 256) {
        unsigned p = lbuf[k];
        int b = p >> 24;
        pairs[gb[b] + (k - bh[b])] = p;
    }
}

// ---- pass B: fine hist+scan in LDS -> off/offE/invdeg, dense ushort ebuf write ----
__global__ __launch_bounds__(256) void passB_kernel(const int* __restrict__ gcur,
                                                    const unsigned* __restrict__ pairs,
                                                    int* __restrict__ off,
                                                    int* __restrict__ offE,
                                                    float* __restrict__ invdeg,
                                                    unsigned short* __restrict__ ebuf16) {
    __shared__ int sc[256];
    __shared__ int fh[256];
    __shared__ int lcnt[256];
    __shared__ unsigned short lout[CAP];
    int b = blockIdx.x;
    int t = threadIdx.x;
    int gb = b * CAP;
    int W = gcur[b];
    fh[t] = 0;
    __syncthreads();
    for (int k = t; k < W; k += 256) atomicAdd(&fh[(pairs[gb + k] >> 16) & 255], 1);
    __syncthreads();
    int c = fh[t];
    sc[t] = c;
    __syncthreads();
    for (int d = 1; d < 256; d <<= 1) {
        int u = (t >= d) ? sc[t - d] : 0;
        __syncthreads();
        sc[t] += u;
        __syncthreads();
    }
    int excl = sc[t] - c;
    int dg = b * 256 + t;
    if (dg < N_NODES) {
        off[dg] = gb + excl;
        offE[dg] = gb + excl + c;
        invdeg[dg] = 1.0f / fmaxf((float)c, 1.0f);
    }
    lcnt[t] = excl;
    __syncthreads();
    for (int k = t; k < W; k += 256) {
        unsigned p = pairs[gb + k];
        int dl = (p >> 16) & 255;
        int pos = atomicAdd(&lcnt[dl], 1);
        lout[pos] = (unsigned short)(p & 0xffffu);
    }
    __syncthreads();
    for (int k = t; k < W; k += 256) ebuf16[gb + k] = lout[k];
}

// ---- layer-1 gather: 4 groups x 16 lanes, 4 edges in flight per group ----
__global__ __launch_bounds__(64) void gather1_kernel(const int* __restrict__ off,
                                                     const int* __restrict__ offE,
                                                     const unsigned short* __restrict__ ebuf,
                                                     const float* __restrict__ invdeg,
                                                     const uint4* __restrict__ xbf4,
                                                     uint4* __restrict__ aggbf4) {
    int d = blockIdx.x;
    int j = threadIdx.x;
    int g = j >> 4;
    int f = j & 15;
    int lo = off[d], hi = offE[d];
    float a[8] = {0.f, 0.f, 0.f, 0.f, 0.f, 0.f, 0.f, 0.f};
    int i = lo + g;
    for (; i + 12 < hi; i += 16) {
        int s0 = ebuf[i], s1 = ebuf[i + 4], s2 = ebuf[i + 8], s3 = ebuf[i + 12];
        uint4 v0 = xbf4[(size_t)s0 * 16 + f];
        uint4 v1 = xbf4[(size_t)s1 * 16 + f];
        uint4 v2 = xbf4[(size_t)s2 * 16 + f];
        uint4 v3 = xbf4[(size_t)s3 * 16 + f];
        a[0] += blo(v0.x) + blo(v1.x) + blo(v2.x) + blo(v3.x);
        a[1] += bhi(v0.x) + bhi(v1.x) + bhi(v2.x) + bhi(v3.x);
        a[2] += blo(v0.y) + blo(v1.y) + blo(v2.y) + blo(v3.y);
        a[3] += bhi(v0.y) + bhi(v1.y) + bhi(v2.y) + bhi(v3.y);
        a[4] += blo(v0.z) + blo(v1.z) + blo(v2.z) + blo(v3.z);
        a[5] += bhi(v0.z) + bhi(v1.z) + bhi(v2.z) + bhi(v3.z);
        a[6] += blo(v0.w) + blo(v1.w) + blo(v2.w) + blo(v3.w);
        a[7] += bhi(v0.w) + bhi(v1.w) + bhi(v2.w) + bhi(v3.w);
    }
    for (; i < hi; i += 4) {
        uint4 v = xbf4[(size_t)ebuf[i] * 16 + f];
        a[0] += blo(v.x); a[1] += bhi(v.x);
        a[2] += blo(v.y); a[3] += bhi(v.y);
        a[4] += blo(v.z); a[5] += bhi(v.z);
        a[6] += blo(v.w); a[7] += bhi(v.w);
    }
#pragma unroll
    for (int q = 0; q < 8; ++q) {
        a[q] += __shfl_xor(a[q], 16, 64);
        a[q] += __shfl_xor(a[q], 32, 64);
    }
    if (g == 0) {
        float inv = invdeg[d];
        uint4 o;
        o.x = (bfbits(a[0] * inv) >> 16) | bfbits(a[1] * inv);
        o.y = (bfbits(a[2] * inv) >> 16) | bfbits(a[3] * inv);
        o.z = (bfbits(a[4] * inv) >> 16) | bfbits(a[5] * inv);
        o.w = (bfbits(a[6] * inv) >> 16) | bfbits(a[7] * inv);
        aggbf4[(size_t)d * 16 + f] = o;
    }
}

// ---- fused MFMA gemm, 2 row-tiles per wave (B-fragments shared):
//      h = relu([agg|x]@Wp1+b1) (LDS), then [p | out] = h@Wp2 (+b2 right) ----
__global__ __launch_bounds__(256) void gemmF_kernel(const unsigned short* __restrict__ aggbf,
                                                    const unsigned short* __restrict__ xbf,
                                                    const unsigned short* __restrict__ Wp1,
                                                    const float* __restrict__ b1,
                                                    const unsigned short* __restrict__ Wp2,
                                                    const float* __restrict__ b2,
                                                    unsigned short* __restrict__ pbf,
                                                    float* __restrict__ out) {
    __shared__ unsigned short hsm[4][2][2048];  // per-wave two 16x128 bf16 tiles
    int w = threadIdx.x >> 6;
    int pairIdx = blockIdx.x * 4 + w;
    int tile0 = pairIdx * 2;
    int tile1 = tile0 + 1;
    bool act0 = tile0 < M_TILES;
    bool act1 = tile1 < M_TILES;
    int t0 = act0 ? tile0 : 0;
    int t1 = act1 ? tile1 : 0;
    int lane = threadIdx.x & 63;
    int lo16 = lane & 15;
    int kg = lane >> 4;
    int r0 = kg * 4;

    // ---- phase 1: [agg|x] @ Wp1 for both tiles ----
    f32x4 accA[8], accB[8];
#pragma unroll
    for (int n = 0; n < 8; ++n) {
        accA[n] = (f32x4){0.f, 0.f, 0.f, 0.f};
        accB[n] = (f32x4){0.f, 0.f, 0.f, 0.f};
    }
    const unsigned short* rowa0 = aggbf + (size_t)(t0 * 16 + lo16) * 128;
    const unsigned short* rowx0 = xbf + (size_t)(t0 * 16 + lo16) * 128;
    const unsigned short* rowa1 = aggbf + (size_t)(t1 * 16 + lo16) * 128;
    const unsigned short* rowx1 = xbf + (size_t)(t1 * 16 + lo16) * 128;
#pragma unroll
    for (int ks = 0; ks < 8; ++ks) {
        int ao = (ks < 4 ? ks * 32 : (ks - 4) * 32) + kg * 8;
        bf16x8 a0 = *reinterpret_cast<const bf16x8*>((ks < 4 ? rowa0 : rowx0) + ao);
        bf16x8 a1 = *reinterpret_cast<const bf16x8*>((ks < 4 ? rowa1 : rowx1) + ao);
        const unsigned short* wbase = Wp1 + ks * 4096 + lo16 * 32 + kg * 8;
#pragma unroll
        for (int n = 0; n < 8; ++n) {
            bf16x8 b = *reinterpret_cast<const bf16x8*>(wbase + n * 512);
            accA[n] = __builtin_amdgcn_mfma_f32_16x16x32_bf16(a0, b, accA[n], 0, 0, 0);
            accB[n] = __builtin_amdgcn_mfma_f32_16x16x32_bf16(a1, b, accB[n], 0, 0, 0);
        }
    }

    // ---- h tiles -> LDS (bias+relu+bf16), XOR-swizzled rows ----
    unsigned short* hs0 = hsm[w][0];
    unsigned short* hs1 = hsm[w][1];
#pragma unroll
    for (int n = 0; n < 8; ++n) {
        int col = n * 16 + lo16;
        float bv = b1[col];
#pragma unroll
        for (int r = 0; r < 4; ++r) {
            int row = r0 + r;
            int sw = (col ^ ((row & 7) << 3));
            hs0[row * 128 + sw] = bf16r(fmaxf(accA[n][r] + bv, 0.0f));
            hs1[row * 128 + sw] = bf16r(fmaxf(accB[n][r] + bv, 0.0f));
        }
    }
    __syncthreads();

    // ---- phase 2: h @ Wp2 from LDS, both tiles ----
    f32x4 acc2A[8], acc2B[8];
#pragma unroll
    for (int n = 0; n < 8; ++n) {
        acc2A[n] = (f32x4){0.f, 0.f, 0.f, 0.f};
        acc2B[n] = (f32x4){0.f, 0.f, 0.f, 0.f};
    }
#pragma unroll
    for (int ks = 0; ks < 4; ++ks) {
        int base0 = (ks * 32 + kg * 8) ^ ((lo16 & 7) << 3);
        bf16x8 a20 = *reinterpret_cast<const bf16x8*>(&hs0[lo16 * 128 + base0]);
        bf16x8 a21 = *reinterpret_cast<const bf16x8*>(&hs1[lo16 * 128 + base0]);
        const unsigned short* wbase = Wp2 + ks * 4096 + lo16 * 32 + kg * 8;
#pragma unroll
        for (int n = 0; n < 8; ++n) {
            bf16x8 b = *reinterpret_cast<const bf16x8*>(wbase + n * 512);
            acc2A[n] = __builtin_amdgcn_mfma_f32_16x16x32_bf16(a20, b, acc2A[n], 0, 0, 0);
            acc2B[n] = __builtin_amdgcn_mfma_f32_16x16x32_bf16(a21, b, acc2B[n], 0, 0, 0);
        }
    }

#pragma unroll
    for (int n = 0; n < 8; ++n) {
        int col = n * 16 + lo16;
        if (col < 64) {
#pragma unroll
            for (int r = 0; r < 4; ++r) {
                if (act0) pbf[(size_t)(tile0 * 16 + r0 + r) * 64 + col] = bf16r(acc2A[n][r]);
                if (act1) pbf[(size_t)(tile1 * 16 + r0 + r) * 64 + col] = bf16r(acc2B[n][r]);
            }
        } else {
            float bv = b2[col - 64];
#pragma unroll
            for (int r = 0; r < 4; ++r) {
                if (act0) out[(size_t)(tile0 * 16 + r0 + r) * 64 + (col - 64)] = acc2A[n][r] + bv;
                if (act1) out[(size_t)(tile1 * 16 + r0 + r) * 64 + (col - 64)] = acc2B[n][r] + bv;
            }
        }
    }
}

// ---- layer-2 gather: 4 groups x 16 lanes, 4 edges in flight per group ----
__global__ __launch_bounds__(64) void gather2_kernel(const int* __restrict__ off,
                                                     const int* __restrict__ offE,
                                                     const unsigned short* __restrict__ ebuf,
                                                     const float* __restrict__ invdeg,
                                                     const uint2* __restrict__ pbf2,
                                                     float4* __restrict__ out4) {
    int d = blockIdx.x;
    int j = threadIdx.x;
    int g = j >> 4;
    int f = j & 15;
    int lo = off[d], hi = offE[d];
    float a0 = 0.f, a1 = 0.f, a2 = 0.f, a3 = 0.f;
    int i = lo + g;
    for (; i + 12 < hi; i += 16) {
        int s0 = ebuf[i], s1 = ebuf[i + 4], s2 = ebuf[i + 8], s3 = ebuf[i + 12];
        uint2 v0 = pbf2[(size_t)s0 * 16 + f];
        uint2 v1 = pbf2[(size_t)s1 * 16 + f];
        uint2 v2 = pbf2[(size_t)s2 * 16 + f];
        uint2 v3 = pbf2[(size_t)s3 * 16 + f];
        a0 += blo(v0.x) + blo(v1.x) + blo(v2.x) + blo(v3.x);
        a1 += bhi(v0.x) + bhi(v1.x) + bhi(v2.x) + bhi(v3.x);
        a2 += blo(v0.y) + blo(v1.y) + blo(v2.y) + blo(v3.y);
        a3 += bhi(v0.y) + bhi(v1.y) + bhi(v2.y) + bhi(v3.y);
    }
    for (; i < hi; i += 4) {
        uint2 v = pbf2[(size_t)ebuf[i] * 16 + f];
        a0 += blo(v.x); a1 += bhi(v.x);
        a2 += blo(v.y); a3 += bhi(v.y);
    }
    a0 += __shfl_xor(a0, 16, 64); a0 += __shfl_xor(a0, 32, 64);
    a1 += __shfl_xor(a1, 16, 64); a1 += __shfl_xor(a1, 32, 64);
    a2 += __shfl_xor(a2, 16, 64); a2 += __shfl_xor(a2, 32, 64);
    a3 += __shfl_xor(a3, 16, 64); a3 += __shfl_xor(a3, 32, 64);
    if (g == 0) {
        float inv = invdeg[d];
        float4* op = out4 + (size_t)d * 16 + f;
        float4 o = *op;
        o.x += a0 * inv;
        o.y += a1 * inv;
        o.z += a2 * inv;
        o.w += a3 * inv;
        *op = o;
    }
}

extern "C" void kernel_launch(void* const* d_in, const int* in_sizes, int n_in,
                              void* d_out, int out_size, void* d_ws, size_t ws_size,
                              hipStream_t stream) {
    const float* x   = (const float*)d_in[0];
    const int*   ei  = (const int*)d_in[1];
    const float* Wl1 = (const float*)d_in[2];
    const float* b1  = (const float*)d_in[3];
    const float* Wr1 = (const float*)d_in[4];
    const float* Wl2 = (const float*)d_in[5];
    const float* b2  = (const float*)d_in[6];
    const float* Wr2 = (const float*)d_in[7];
    float* out = (float*)d_out;

    const int E = in_sizes[1] / 2;
    const int* src = ei;
    const int* dst = ei + E;

    char* ws = (char*)d_ws;
    int*            off    = (int*)(ws + OFF_OFF);
    int*            offE   = (int*)(ws + OFFE_OFF);
    unsigned short* ebuf16 = (unsigned short*)(ws + EBUF_OFF);
    int*            gcur   = (int*)(ws + GCUR_OFF);
    float*          invdeg = (float*)(ws + INV_OFF);
    unsigned*       xbf    = (unsigned*)(ws + XBF_OFF);
    unsigned*       aggbf  = (unsigned*)(ws + AGG_OFF);
    unsigned*       pairs  = (unsigned*)(ws + PAIRS_OFF);
    unsigned short* pbf    = (unsigned short*)(ws + PBF_OFF);
    unsigned short* Wp1    = (unsigned short*)(ws + WP1_OFF);
    unsigned short* Wp2    = (unsigned short*)(ws + WP2_OFF);

    // fused conversion + weight packing + gcur zeroing
    prep_kernel<<<CONV_BLOCKS + 192, 256, 0, stream>>>((const float4*)x, (uint2*)xbf, gcur,
                                                       Wl1, Wr1, Wl2, Wr2, Wp1, Wp2);

    // dst-CSR build: fixed-capacity coarse partition -> fine order (+off/offE/invdeg)
    passA_kernel<<<(E + CHUNK_A - 1) / CHUNK_A, 256, 0, stream>>>(src, dst, gcur, pairs, E);
    passB_kernel<<<NBUCKET, 256, 0, stream>>>(gcur, pairs, off, offE, invdeg, ebuf16);

    // layer 1 aggregate
    gather1_kernel<<<N_NODES, 64, 0, stream>>>(off, offE, ebuf16, invdeg, (const uint4*)xbf,
                                               (uint4*)aggbf);

    // fused layer-1 + layer-2 dense (h stays in LDS, 2 tiles/wave)
    gemmF_kernel<<<(((M_TILES + 1) / 2) + 3) / 4, 256, 0, stream>>>(
        (const unsigned short*)aggbf, (const unsigned short*)xbf,
        Wp1, b1, Wp2, b2, pbf, out);

    // layer 2 aggregate (project-then-aggregate)
    gather2_kernel<<<N_NODES, 64, 0, stream>>>(off, offE, ebuf16, invdeg, (const uint2*)pbf,
                                               (float4*)out);
}